// Round 12
// baseline (7435.065 us; speedup 1.0000x reference)
//
#include <hip/hip_runtime.h>

#define V_ 32000
#define E_ 256
#define H_ 512
#define B_ 32
#define S_ 128
#define T_ 64
#define TD_ 63        // decoder steps (T-1)
#define G3_ 1536      // 3*H
#define CATK_ 1792    // H + E + 2H
#define DIN_ 1280     // E + 2H
#define MPAD_ 2048    // padded M for fc1 MFMA

typedef __attribute__((ext_vector_type(8))) short bf16x8;
typedef __attribute__((ext_vector_type(4))) float f32x4;

__device__ inline unsigned short bf16_rne(float x) {
    unsigned u = __float_as_uint(x);
    unsigned r = u + 0x7FFFu + ((u >> 16) & 1u);
    return (unsigned short)(r >> 16);
}

// agent-scope ops: coherence-point access, no cache invalidation (r5-proven)
__device__ __forceinline__ float ato_ldf(const float* p) {
    return __hip_atomic_load((const float*)p, __ATOMIC_RELAXED, __HIP_MEMORY_SCOPE_AGENT);
}
__device__ __forceinline__ void ato_stf(float* p, float v) {
    __hip_atomic_store(p, v, __ATOMIC_RELAXED, __HIP_MEMORY_SCOPE_AGENT);
}

// ---------------------------------------------------------------------------
// Single-level GROUP barrier (batch-pair groups are fully independent):
// one cacheline per group: cnt @ gbase, gen @ gbase+32. Fence-free (data goes
// through agent atomics; vmcnt(0) drains stores before arrival).
// ---------------------------------------------------------------------------
__device__ __forceinline__ void group_bar(unsigned* gbase, unsigned nb)
{
    asm volatile("s_waitcnt vmcnt(0)" ::: "memory");
    __syncthreads();
    if (threadIdx.x == 0) {
        unsigned* cnt = gbase;
        unsigned* gen = gbase + 32;
        unsigned g0 = __hip_atomic_load(gen, __ATOMIC_RELAXED, __HIP_MEMORY_SCOPE_AGENT);
        unsigned a  = __hip_atomic_fetch_add(cnt, 1u, __ATOMIC_RELAXED, __HIP_MEMORY_SCOPE_AGENT);
        if (a == nb - 1u) {
            __hip_atomic_store(cnt, 0u, __ATOMIC_RELAXED, __HIP_MEMORY_SCOPE_AGENT);
            __hip_atomic_store(gen, g0 + 1u, __ATOMIC_RELAXED, __HIP_MEMORY_SCOPE_AGENT);
        } else {
            while (__hip_atomic_load(gen, __ATOMIC_RELAXED, __HIP_MEMORY_SCOPE_AGENT) == g0)
                __builtin_amdgcn_s_sleep(1);
        }
    }
    __syncthreads();
}

// ---------------------------------------------------------------------------
__global__ __launch_bounds__(256)
void prep_kernel(const int* __restrict__ src, const int* __restrict__ tgt,
                 int* __restrict__ tokf, int* __restrict__ tokb, int* __restrict__ tokd,
                 float* __restrict__ h_enc, unsigned* __restrict__ bars)
{
    int tid = blockIdx.x * 256 + threadIdx.x;
    if (tid < S_ * B_) {
        int s = tid >> 5, b = tid & 31;
        tokf[tid] = src[b * S_ + s];
        tokb[tid] = src[b * S_ + (S_ - 1 - s)];
    }
    if (tid < TD_ * B_) {
        int t = tid >> 5, b = tid & 31;
        tokd[tid] = tgt[b * T_ + t];
    }
    if (tid < 2 * 2 * B_ * H_) h_enc[tid] = 0.f;   // [dir][pp][b][k], all slots
    if (tid < 4096) bars[tid] = 0u;
}

// ---------------------------------------------------------------------------
__global__ __launch_bounds__(256)
void emb_cat_kernel(const int* __restrict__ tokd, const float* __restrict__ dec_emb,
                    float* __restrict__ cat)
{
    int row = blockIdx.x;          // row = t*32 + b
    int tid = threadIdx.x;         // 0..255 == E_
    cat[(size_t)row * CATK_ + H_ + tid] = dec_emb[(size_t)tokd[row] * E_ + tid];
}

// ---------------------------------------------------------------------------
// Generic fp32 GEMM (small GEMMs + fallback fc1)
// ---------------------------------------------------------------------------
template<int GATHER, int FC1MAP>
__global__ __launch_bounds__(256)
void gemm128_kernel(const float* __restrict__ A, int lda,
                    const int* __restrict__ tokens, const float* __restrict__ emb,
                    const float* __restrict__ W, int ldw,
                    const float* __restrict__ bias,
                    float* __restrict__ C, int ldc,
                    int M, int N, int K)
{
    __shared__ float As[16][132];
    __shared__ float Ws[16][132];
    (void)N;
    int tid = threadIdx.x;
    int m0 = blockIdx.y * 128, n0 = blockIdx.x * 128;
    int tx = tid & 15, ty = tid >> 4;
    float c[8][8];
#pragma unroll
    for (int i = 0; i < 8; i++)
#pragma unroll
        for (int j = 0; j < 8; j++) c[i][j] = 0.f;

    int arow = tid >> 1;
    int kq = (tid & 1) * 8;

    int am = m0 + arow; if (am >= M) am = M - 1;
    const float* arp;
    if (GATHER) arp = emb + (size_t)tokens[am] * (size_t)K;
    else        arp = A + (size_t)am * (size_t)lda;
    const float* wrp = W + (size_t)(n0 + arow) * (size_t)ldw;

    for (int kb = 0; kb < K; kb += 16) {
        __syncthreads();
        float4 a0 = *(const float4*)(arp + kb + kq);
        float4 a1 = *(const float4*)(arp + kb + kq + 4);
        float4 w0 = *(const float4*)(wrp + kb + kq);
        float4 w1 = *(const float4*)(wrp + kb + kq + 4);
        As[kq + 0][arow] = a0.x; As[kq + 1][arow] = a0.y;
        As[kq + 2][arow] = a0.z; As[kq + 3][arow] = a0.w;
        As[kq + 4][arow] = a1.x; As[kq + 5][arow] = a1.y;
        As[kq + 6][arow] = a1.z; As[kq + 7][arow] = a1.w;
        Ws[kq + 0][arow] = w0.x; Ws[kq + 1][arow] = w0.y;
        Ws[kq + 2][arow] = w0.z; Ws[kq + 3][arow] = w0.w;
        Ws[kq + 4][arow] = w1.x; Ws[kq + 5][arow] = w1.y;
        Ws[kq + 6][arow] = w1.z; Ws[kq + 7][arow] = w1.w;
        __syncthreads();
#pragma unroll
        for (int kk = 0; kk < 16; kk++) {
            float a[8], bb[8];
            *(float4*)&a[0]  = *(const float4*)&As[kk][ty * 8];
            *(float4*)&a[4]  = *(const float4*)&As[kk][ty * 8 + 4];
            *(float4*)&bb[0] = *(const float4*)&Ws[kk][tx * 8];
            *(float4*)&bb[4] = *(const float4*)&Ws[kk][tx * 8 + 4];
#pragma unroll
            for (int i = 0; i < 8; i++)
#pragma unroll
                for (int j = 0; j < 8; j++) c[i][j] += a[i] * bb[j];
        }
    }

#pragma unroll
    for (int i = 0; i < 8; i++) {
        int m = m0 + ty * 8 + i;
        if (m < M) {
            size_t rowoff;
            if (FC1MAP) { int tt = m >> 5, bb2 = m & 31; rowoff = ((size_t)bb2 * T_ + tt) * (size_t)ldc; }
            else        rowoff = (size_t)m * (size_t)ldc;
#pragma unroll
            for (int j = 0; j < 8; j += 4) {
                int n = n0 + tx * 8 + j;
                float4 v;
                v.x = c[i][j + 0] + bias[n + 0];
                v.y = c[i][j + 1] + bias[n + 1];
                v.z = c[i][j + 2] + bias[n + 2];
                v.w = c[i][j + 3] + bias[n + 3];
                *(float4*)(C + rowoff + n) = v;
            }
        }
    }
}

// ---------------------------------------------------------------------------
// PERSISTENT bi-GRU encoder v12: 128 blocks = (bp 16) x (kq 8).
// Group = 8 blocks of one bp (batch-pair) - batches are independent, so only
// an 8-block barrier per step. Block handles BOTH dirs, k-slice 64.
// kq = bid%8 -> XCD locality: the 768 KB weight slice stays L2-resident.
// h state: fixed slots [dir][pp][b][k] via agent atomics (tiny: 8 KB/blk/step).
// Tail: enc_fc for own batches/i-slice (group-local) -> hT0 [b][k].
// ---------------------------------------------------------------------------
__global__ __launch_bounds__(256)
void enc_coop_kernel(const float* __restrict__ gxf, const float* __restrict__ gxb,
                     const float* __restrict__ Whh_f, const float* __restrict__ bhh_f,
                     const float* __restrict__ Whh_b, const float* __restrict__ bhh_b,
                     float* __restrict__ h_enc, float* __restrict__ enc_bt,
                     const float* __restrict__ fcW, const float* __restrict__ fcb,
                     float* __restrict__ hT0, unsigned* __restrict__ bars)
{
    const int bid = blockIdx.x, tid = threadIdx.x;
    const int bp = bid >> 3, kq = bid & 7;
    const int b0 = bp * 2, b1 = b0 + 1;
    const int k0 = kq * 64;
    __shared__ float hS[4][512];          // [dir*2+b2][j]
    __shared__ float egA[384], egB[384];  // row-gate partials for b0 / b1
    unsigned* gbar = bars + bp * 64;

    for (int t = 0; t < S_; ++t) {
        const int pp = t & 1;
        const float* hin0 = h_enc + (size_t)(0 * 2 + pp) * B_ * H_;   // dir0
        const float* hin1 = h_enc + (size_t)(1 * 2 + pp) * B_ * H_;   // dir1
        for (int j = tid; j < H_; j += 256) {
            hS[0][j] = ato_ldf(hin0 + (size_t)b0 * H_ + j);
            hS[1][j] = ato_ldf(hin0 + (size_t)b1 * H_ + j);
            hS[2][j] = ato_ldf(hin1 + (size_t)b0 * H_ + j);
            hS[3][j] = ato_ldf(hin1 + (size_t)b1 * H_ + j);
        }
        __syncthreads();
        // 384 row-dots (2dir x 3gate x 64k), dual-batch
        for (int r = tid; r < 384; r += 256) {
            int dir = r / 192, rr = r - dir * 192;
            int grow = (rr >> 6) * H_ + k0 + (rr & 63);
            const float* wrow = (dir ? Whh_b : Whh_f) + (size_t)grow * H_;
            const float* h0 = hS[dir * 2 + 0];
            const float* h1 = hS[dir * 2 + 1];
            float a00 = 0.f, a01 = 0.f, a10 = 0.f, a11 = 0.f;
            for (int j = 0; j < H_; j += 8) {
                float4 w0 = *(const float4*)(wrow + j);
                float4 w1 = *(const float4*)(wrow + j + 4);
                float4 x0 = *(const float4*)&h0[j];
                float4 x1 = *(const float4*)&h0[j + 4];
                float4 y0 = *(const float4*)&h1[j];
                float4 y1 = *(const float4*)&h1[j + 4];
                a00 += w0.x * x0.x + w0.y * x0.y + w0.z * x0.z + w0.w * x0.w;
                a01 += w1.x * x1.x + w1.y * x1.y + w1.z * x1.z + w1.w * x1.w;
                a10 += w0.x * y0.x + w0.y * y0.y + w0.z * y0.z + w0.w * y0.w;
                a11 += w1.x * y1.x + w1.y * y1.y + w1.z * y1.z + w1.w * y1.w;
            }
            float bb = (dir ? bhh_b : bhh_f)[grow];
            egA[r] = a00 + a01 + bb;
            egB[r] = a10 + a11 + bb;
        }
        __syncthreads();
        // gates: thread = (dir, b2, kk); 2*2*64 = 256 exactly
        {
            int dir = tid >> 7, b2 = (tid >> 6) & 1, kk = tid & 63;
            int k = k0 + kk;
            int b = b2 ? b1 : b0;
            int rb = dir * 192;
            const float* eg = b2 ? egB : egA;
            float hr = eg[rb + kk], hz = eg[rb + 64 + kk], hn = eg[rb + 128 + kk];
            const float* gx = dir ? gxb : gxf;
            const float* gxr = gx + ((size_t)t * B_ + b) * G3_;
            float xr = gxr[k], xz = gxr[H_ + k], xn = gxr[2 * H_ + k];
            float rg = 1.f / (1.f + expf(-(xr + hr)));
            float zg = 1.f / (1.f + expf(-(xz + hz)));
            float ng = tanhf(xn + rg * hn);
            float hp = hS[dir * 2 + b2][k];
            float h2 = (1.f - zg) * ng + zg * hp;
            float* hout = h_enc + (size_t)(dir * 2 + 1 - pp) * B_ * H_;
            ato_stf(hout + (size_t)b * H_ + k, h2);
            int s_out = dir ? (S_ - 1 - t) : t;
            enc_bt[((size_t)b * S_ + s_out) * (2 * H_) + dir * H_ + k] = h2;
        }
        group_bar(gbar, 8);
    }

    // tail: hidden = tanh([hf,hb] @ fcW.T + fcb) for own batches, i-slice 64
    // final h is in pp=0 slots (S_=128 even). Group-local (no global barrier).
    {
        float* hc0 = &hS[0][0];   // 1024 floats: [hf(b0), hb(b0)]
        float* hc1 = &hS[2][0];   // 1024 floats: [hf(b1), hb(b1)]
        const float* hf0 = h_enc + (size_t)0 * B_ * H_;            // dir0 pp0
        const float* hf1 = h_enc + (size_t)2 * B_ * H_;            // dir1 pp0
        for (int j = tid; j < H_; j += 256) {
            hc0[j] = ato_ldf(hf0 + (size_t)b0 * H_ + j);
            hc0[H_ + j] = ato_ldf(hf1 + (size_t)b0 * H_ + j);
            hc1[j] = ato_ldf(hf0 + (size_t)b1 * H_ + j);
            hc1[H_ + j] = ato_ldf(hf1 + (size_t)b1 * H_ + j);
        }
        __syncthreads();
        if (tid < 128) {
            int b2 = tid >> 6, ii = tid & 63;
            int i = k0 + ii;
            int b = b2 ? b1 : b0;
            const float* hc = b2 ? hc1 : hc0;
            const float* w = fcW + (size_t)i * (2 * H_);
            float acc = 0.f;
            for (int j = 0; j < 2 * H_; j += 4) {
                float4 a4 = *(const float4*)&hc[j];
                float4 w4 = *(const float4*)(w + j);
                acc += a4.x * w4.x + a4.y * w4.y + a4.z * w4.z + a4.w * w4.w;
            }
            ato_stf(hT0 + (size_t)b * H_ + i, tanhf(acc + fcb[i]));
        }
    }
}

// ---------------------------------------------------------------------------
// PERSISTENT attention decoder v12: 256 blocks = (bp 16) x (kr 16).
// Group = 16 blocks of one bp; ALL cross-block deps are intra-group ->
// 16-block single-level barriers (4/step).
// P0 (all): h cols (atomics) -> hwh (32 W_h rows -> global) + ghh (96, LDS).
// P1 (kr<8): attention s-QUARTER (ab=b0+(kr>>2), q=kr&3, 32 s): scores with
//     padded LDS (conflict-free) -> online-softmax partial (m,l) + wpart.
// P1b (kr==8,9): combine 4 quarters (exact) -> wT + cat w-cols.
// P2 (all): w cols (atomics) -> xw (96 Wih rows, LDS) -> gates -> h' + cat.
// ---------------------------------------------------------------------------
__global__ __launch_bounds__(256)
void dec_coop_kernel(const float* __restrict__ attn_W, const float* __restrict__ attn_v,
                     const float* __restrict__ enc_projB, const float* __restrict__ enc_bt,
                     const int* __restrict__ src,
                     const float* __restrict__ dWhh, const float* __restrict__ dbhh,
                     const float* __restrict__ dWih, const float* __restrict__ gx_emb,
                     float* __restrict__ cat, float* __restrict__ hT,
                     float* __restrict__ hwhT, float* __restrict__ wT,
                     float* __restrict__ wpart, float* __restrict__ mlq,
                     unsigned* __restrict__ bars)
{
    const int bid = blockIdx.x, tid = threadIdx.x;
    const int bp = bid >> 4, kr = bid & 15;
    const int b0 = bp * 2, b1 = b0 + 1;
    const int k0 = kr * 32;
    __shared__ float hA[512], hB[512];
    __shared__ float ghhA[96], ghhB[96];
    __shared__ float xwA[96], xwB[96];
    __shared__ float wA[1024], wB[1024];
    __shared__ float hwP[8 * 68], vP[8 * 68];    // padded: conflict-free
    __shared__ float sL[32], eS[32], cmb[8];
    unsigned* gbar = bars + bp * 64;

    const int p1act = (kr < 8);
    const int p1ab  = b0 + (kr >> 2);            // P1 batch
    const int p1q   = kr & 3;                    // s-quarter
    const int cact  = (kr == 8 || kr == 9);
    const int cb    = b0 + (kr - 8);             // P1b batch
    const int r0 = tid >> 1, b2_0 = tid & 1;     // P0 task

    for (int t = 0; t < TD_; ++t) {
        const int pp = t & 1;
        const float* hin = hT + (size_t)pp * (B_ * H_);
        float* hout = hT + (size_t)(1 - pp) * (B_ * H_);
        float* cat_t = cat + (size_t)t * B_ * CATK_;

        // ---- P0: hwh (global) + ghh (LDS-local) ----
        for (int j = tid; j < H_; j += 256) {
            hA[j] = ato_ldf(hin + (size_t)b0 * H_ + j);
            hB[j] = ato_ldf(hin + (size_t)b1 * H_ + j);
        }
        __syncthreads();
        {
            const float* hv = b2_0 ? hB : hA;
            const float* wrow;
            if (r0 < 32) wrow = attn_W + (size_t)(k0 + r0) * G3_;
            else {
                int rr = r0 - 32;
                wrow = dWhh + (size_t)((rr >> 5) * H_ + k0 + (rr & 31)) * H_;
            }
            float a0 = 0.f, a1 = 0.f;
            for (int j = 0; j < H_; j += 8) {
                float4 w0 = *(const float4*)(wrow + j);
                float4 w1 = *(const float4*)(wrow + j + 4);
                float4 h0 = *(const float4*)&hv[j];
                float4 h1 = *(const float4*)&hv[j + 4];
                a0 += w0.x * h0.x + w0.y * h0.y + w0.z * h0.z + w0.w * h0.w;
                a1 += w1.x * h1.x + w1.y * h1.y + w1.z * h1.z + w1.w * h1.w;
            }
            float acc = a0 + a1;
            int b = b2_0 ? b1 : b0;
            if (r0 < 32) ato_stf(hwhT + (size_t)b * H_ + k0 + r0, acc);
            else {
                int rr = r0 - 32;
                float* g = b2_0 ? ghhB : ghhA;
                g[rr] = acc + dbhh[(rr >> 5) * H_ + k0 + (rr & 31)];
            }
        }
        group_bar(gbar, 16);

        // ---- P1: scores + online-softmax partial + wpart (s-quarter) ----
        if (p1act) {
            const int ab = p1ab;
            const int s0 = p1q * 32;
            for (int i = tid; i < H_; i += 256) {
                int pi = (i >> 6) * 68 + (i & 63);
                hwP[pi] = ato_ldf(hwhT + (size_t)ab * H_ + i);
                vP[pi]  = attn_v[i];
            }
            __syncthreads();
            {
                int s = tid >> 3, u = tid & 7;
                const float* pr = enc_projB + ((size_t)ab * S_ + s0 + s) * H_ + u * 64;
                const float* hwo = hwP + u * 68;
                const float* vo  = vP + u * 68;
                float a0 = 0.f, a1 = 0.f, a2 = 0.f, a3 = 0.f;
#pragma unroll
                for (int i = 0; i < 64; i += 4) {
                    float4 p4 = *(const float4*)(pr + i);
                    float4 h4 = *(const float4*)(hwo + i);
                    float4 v4 = *(const float4*)(vo + i);
                    float x0 = h4.x + p4.x, x1 = h4.y + p4.y;
                    float x2 = h4.z + p4.z, x3 = h4.w + p4.w;
                    a0 += v4.x * (1.f - 2.f / (__expf(2.f * x0) + 1.f));
                    a1 += v4.y * (1.f - 2.f / (__expf(2.f * x1) + 1.f));
                    a2 += v4.z * (1.f - 2.f / (__expf(2.f * x2) + 1.f));
                    a3 += v4.w * (1.f - 2.f / (__expf(2.f * x3) + 1.f));
                }
                float acc = (a0 + a1) + (a2 + a3);
                acc += __shfl_xor(acc, 1);
                acc += __shfl_xor(acc, 2);
                acc += __shfl_xor(acc, 4);
                if (u == 0) sL[s] = (src[ab * S_ + s0 + s] != 0) ? acc : -1e10f;
            }
            __syncthreads();
            if (tid < 32) {
                float v = sL[tid];
                float m = v;
#pragma unroll
                for (int off = 1; off < 32; off <<= 1) m = fmaxf(m, __shfl_xor(m, off));
                float e = expf(v - m);
                eS[tid] = e;
                float l = e;
#pragma unroll
                for (int off = 1; off < 32; off <<= 1) l += __shfl_xor(l, off);
                if (tid == 0) {
                    ato_stf(mlq + (size_t)(ab * 4 + p1q) * 2 + 0, m);
                    ato_stf(mlq + (size_t)(ab * 4 + p1q) * 2 + 1, l);
                }
            }
            __syncthreads();
            {
                int c4 = tid * 4;
                const float* eb = enc_bt + ((size_t)ab * S_ + s0) * (2 * H_) + c4;
                float4 ac0 = {0, 0, 0, 0}, ac1 = {0, 0, 0, 0};
                float4 ac2 = {0, 0, 0, 0}, ac3 = {0, 0, 0, 0};
                for (int s = 0; s < 32; s += 4) {
                    float4 v0 = *(const float4*)(eb + (size_t)(s + 0) * (2 * H_));
                    float4 v1 = *(const float4*)(eb + (size_t)(s + 1) * (2 * H_));
                    float4 v2 = *(const float4*)(eb + (size_t)(s + 2) * (2 * H_));
                    float4 v3 = *(const float4*)(eb + (size_t)(s + 3) * (2 * H_));
                    float e0 = eS[s], e1 = eS[s + 1], e2 = eS[s + 2], e3 = eS[s + 3];
                    ac0.x += e0 * v0.x; ac0.y += e0 * v0.y; ac0.z += e0 * v0.z; ac0.w += e0 * v0.w;
                    ac1.x += e1 * v1.x; ac1.y += e1 * v1.y; ac1.z += e1 * v1.z; ac1.w += e1 * v1.w;
                    ac2.x += e2 * v2.x; ac2.y += e2 * v2.y; ac2.z += e2 * v2.z; ac2.w += e2 * v2.w;
                    ac3.x += e3 * v3.x; ac3.y += e3 * v3.y; ac3.z += e3 * v3.z; ac3.w += e3 * v3.w;
                }
                float* dst = wpart + (size_t)(ab * 4 + p1q) * 1024 + c4;
                ato_stf(dst + 0, (ac0.x + ac1.x) + (ac2.x + ac3.x));
                ato_stf(dst + 1, (ac0.y + ac1.y) + (ac2.y + ac3.y));
                ato_stf(dst + 2, (ac0.z + ac1.z) + (ac2.z + ac3.z));
                ato_stf(dst + 3, (ac0.w + ac1.w) + (ac2.w + ac3.w));
            }
        }
        group_bar(gbar, 16);

        // ---- P1b: combine quarters -> wT + cat w-cols ----
        if (cact) {
            const int ab = cb;
            if (tid < 4) {
                cmb[tid] = ato_ldf(mlq + (size_t)(ab * 4 + tid) * 2 + 0);
                cmb[4 + tid] = ato_ldf(mlq + (size_t)(ab * 4 + tid) * 2 + 1);
            }
            __syncthreads();
            float m = fmaxf(fmaxf(cmb[0], cmb[1]), fmaxf(cmb[2], cmb[3]));
            float e0 = expf(cmb[0] - m), e1 = expf(cmb[1] - m);
            float e2 = expf(cmb[2] - m), e3 = expf(cmb[3] - m);
            float L = e0 * cmb[4] + e1 * cmb[5] + e2 * cmb[6] + e3 * cmb[7];
            float inv = 1.f / L;
            int c4 = tid * 4;
            const float* p0 = wpart + (size_t)(ab * 4 + 0) * 1024 + c4;
            const float* p1 = wpart + (size_t)(ab * 4 + 1) * 1024 + c4;
            const float* p2 = wpart + (size_t)(ab * 4 + 2) * 1024 + c4;
            const float* p3 = wpart + (size_t)(ab * 4 + 3) * 1024 + c4;
            float4 w4;
            w4.x = (e0 * ato_ldf(p0 + 0) + e1 * ato_ldf(p1 + 0) + e2 * ato_ldf(p2 + 0) + e3 * ato_ldf(p3 + 0)) * inv;
            w4.y = (e0 * ato_ldf(p0 + 1) + e1 * ato_ldf(p1 + 1) + e2 * ato_ldf(p2 + 1) + e3 * ato_ldf(p3 + 1)) * inv;
            w4.z = (e0 * ato_ldf(p0 + 2) + e1 * ato_ldf(p1 + 2) + e2 * ato_ldf(p2 + 2) + e3 * ato_ldf(p3 + 2)) * inv;
            w4.w = (e0 * ato_ldf(p0 + 3) + e1 * ato_ldf(p1 + 3) + e2 * ato_ldf(p2 + 3) + e3 * ato_ldf(p3 + 3)) * inv;
            ato_stf(wT + (size_t)ab * 1024 + c4 + 0, w4.x);
            ato_stf(wT + (size_t)ab * 1024 + c4 + 1, w4.y);
            ato_stf(wT + (size_t)ab * 1024 + c4 + 2, w4.z);
            ato_stf(wT + (size_t)ab * 1024 + c4 + 3, w4.w);
            *(float4*)(cat_t + (size_t)ab * CATK_ + (H_ + E_) + c4) = w4;
        }
        group_bar(gbar, 16);

        // ---- P2: xw (LDS-local) -> gates -> h' + cat ----
        for (int c = tid; c < 2 * H_; c += 256) {
            wA[c] = ato_ldf(wT + (size_t)b0 * 1024 + c);
            wB[c] = ato_ldf(wT + (size_t)b1 * 1024 + c);
        }
        __syncthreads();
        if (tid < 192) {
            int rr = tid >> 1, b2 = tid & 1;
            const float* wv = b2 ? wB : wA;
            const float* wrow = dWih + (size_t)((rr >> 5) * H_ + k0 + (rr & 31)) * DIN_ + E_;
            float a0 = 0.f, a1 = 0.f;
            for (int c = 0; c < 2 * H_; c += 8) {
                float4 w0 = *(const float4*)(wrow + c);
                float4 w1 = *(const float4*)(wrow + c + 4);
                float4 x0 = *(const float4*)&wv[c];
                float4 x1 = *(const float4*)&wv[c + 4];
                a0 += w0.x * x0.x + w0.y * x0.y + w0.z * x0.z + w0.w * x0.w;
                a1 += w1.x * x1.x + w1.y * x1.y + w1.z * x1.z + w1.w * x1.w;
            }
            (b2 ? xwB : xwA)[rr] = a0 + a1;
        }
        __syncthreads();
        if (tid < 64) {
            int b2 = tid >> 5, kk = tid & 31;
            int b = b2 ? b1 : b0;
            int k = k0 + kk;
            const float* g = b2 ? ghhB : ghhA;
            const float* x = b2 ? xwB : xwA;
            float hr = g[kk], hz = g[32 + kk], hn = g[64 + kk];
            float xr = x[kk], xz = x[32 + kk], xn = x[64 + kk];
            const float* gxe = gx_emb + ((size_t)t * B_ + b) * G3_;
            float rg = 1.f / (1.f + expf(-(gxe[k] + xr + hr)));
            float zg = 1.f / (1.f + expf(-(gxe[H_ + k] + xz + hz)));
            float ng = tanhf(gxe[2 * H_ + k] + xn + rg * hn);
            float hp = b2 ? hB[k] : hA[k];
            float h2 = (1.f - zg) * ng + zg * hp;
            ato_stf(hout + (size_t)b * H_ + k, h2);
            cat_t[(size_t)b * CATK_ + k] = h2;
        }
        group_bar(gbar, 16);
    }
}

// ---------------------------------------------------------------------------
__global__ __launch_bounds__(256)
void splitA_kernel(const float* __restrict__ cat,
                   unsigned short* __restrict__ Ahi, unsigned short* __restrict__ Alo)
{
    size_t i4 = ((size_t)blockIdx.x * 256 + threadIdx.x) * 4;
    if (i4 >= (size_t)MPAD_ * CATK_) return;
    size_t row = i4 / CATK_;
    float4 v;
    if (row < (size_t)TD_ * B_) v = *(const float4*)(cat + i4);
    else { v.x = v.y = v.z = v.w = 0.f; }
    float f[4] = {v.x, v.y, v.z, v.w};
    unsigned short h[4], l[4];
#pragma unroll
    for (int j = 0; j < 4; j++) {
        h[j] = bf16_rne(f[j]);
        float hf = __uint_as_float((unsigned)h[j] << 16);
        l[j] = bf16_rne(f[j] - hf);
    }
    *(ushort4*)(Ahi + i4) = make_ushort4(h[0], h[1], h[2], h[3]);
    *(ushort4*)(Alo + i4) = make_ushort4(l[0], l[1], l[2], l[3]);
}

// ---------------------------------------------------------------------------
__global__ __launch_bounds__(256)
void fc1_mfma_kernel(const unsigned short* __restrict__ Ahi,
                     const unsigned short* __restrict__ Alo,
                     const float* __restrict__ W,
                     const float* __restrict__ bias,
                     float* __restrict__ C)
{
    __shared__ unsigned short lA[2][128][40];
    __shared__ unsigned short lW[2][128][40];
    const int tid = threadIdx.x;
    const int m0 = blockIdx.x * 128, n0 = blockIdx.y * 128;
    const int w = tid >> 6, lane = tid & 63;
    const int wm = w >> 1, wn = w & 1;
    const int frow = lane & 15, fk = (lane >> 4) * 8;

    f32x4 acc[4][4];
#pragma unroll
    for (int mi = 0; mi < 4; mi++)
#pragma unroll
        for (int ni = 0; ni < 4; ni++) acc[mi][ni] = (f32x4){0.f, 0.f, 0.f, 0.f};

    const int srow = tid >> 1;
    const int skq = (tid & 1) * 16;

    const unsigned short* gAhi = Ahi + (size_t)(m0 + srow) * CATK_ + skq;
    const unsigned short* gAlo = Alo + (size_t)(m0 + srow) * CATK_ + skq;
    const float*          gW   = W   + (size_t)(n0 + srow) * CATK_ + skq;

    int4 rAh0, rAh1, rAl0, rAl1;
    float4 rW0, rW1, rW2, rW3;

#define FC1_LOAD(kb)                                        \
    do {                                                    \
        rAh0 = *(const int4*)(gAhi + (kb));                 \
        rAh1 = *(const int4*)(gAhi + (kb) + 8);             \
        rAl0 = *(const int4*)(gAlo + (kb));                 \
        rAl1 = *(const int4*)(gAlo + (kb) + 8);             \
        rW0  = *(const float4*)(gW + (kb));                 \
        rW1  = *(const float4*)(gW + (kb) + 4);             \
        rW2  = *(const float4*)(gW + (kb) + 8);             \
        rW3  = *(const float4*)(gW + (kb) + 12);            \
    } while (0)

    FC1_LOAD(0);

    for (int kb = 0; kb < CATK_; kb += 32) {
        __syncthreads();
        *(int4*)&lA[0][srow][skq]     = rAh0;
        *(int4*)&lA[0][srow][skq + 8] = rAh1;
        *(int4*)&lA[1][srow][skq]     = rAl0;
        *(int4*)&lA[1][srow][skq + 8] = rAl1;
        {
            float f[16] = {rW0.x, rW0.y, rW0.z, rW0.w, rW1.x, rW1.y, rW1.z, rW1.w,
                           rW2.x, rW2.y, rW2.z, rW2.w, rW3.x, rW3.y, rW3.z, rW3.w};
            unsigned hp[8], lp[8];
#pragma unroll
            for (int j = 0; j < 8; j++) {
                float x0 = f[2 * j], x1 = f[2 * j + 1];
                unsigned short h0 = bf16_rne(x0), h1 = bf16_rne(x1);
                float r0 = x0 - __uint_as_float((unsigned)h0 << 16);
                float r1 = x1 - __uint_as_float((unsigned)h1 << 16);
                hp[j] = (unsigned)h0 | ((unsigned)h1 << 16);
                lp[j] = (unsigned)bf16_rne(r0) | ((unsigned)bf16_rne(r1) << 16);
            }
            *(int4*)&lW[0][srow][skq]     = make_int4(hp[0], hp[1], hp[2], hp[3]);
            *(int4*)&lW[0][srow][skq + 8] = make_int4(hp[4], hp[5], hp[6], hp[7]);
            *(int4*)&lW[1][srow][skq]     = make_int4(lp[0], lp[1], lp[2], lp[3]);
            *(int4*)&lW[1][srow][skq + 8] = make_int4(lp[4], lp[5], lp[6], lp[7]);
        }
        __syncthreads();
        if (kb + 32 < CATK_) FC1_LOAD(kb + 32);

        bf16x8 a[2][4];
#pragma unroll
        for (int mi = 0; mi < 4; mi++) {
            int r = wm * 64 + mi * 16 + frow;
            a[0][mi] = *(const bf16x8*)&lA[0][r][fk];
            a[1][mi] = *(const bf16x8*)&lA[1][r][fk];
        }
#pragma unroll
        for (int ni = 0; ni < 4; ni++) {
            int r = wn * 64 + ni * 16 + frow;
            bf16x8 bh = *(const bf16x8*)&lW[0][r][fk];
            bf16x8 bl = *(const bf16x8*)&lW[1][r][fk];
#pragma unroll
            for (int mi = 0; mi < 4; mi++) {
                acc[mi][ni] = __builtin_amdgcn_mfma_f32_16x16x32_bf16(a[0][mi], bh, acc[mi][ni], 0, 0, 0);
                acc[mi][ni] = __builtin_amdgcn_mfma_f32_16x16x32_bf16(a[1][mi], bh, acc[mi][ni], 0, 0, 0);
                acc[mi][ni] = __builtin_amdgcn_mfma_f32_16x16x32_bf16(a[0][mi], bl, acc[mi][ni], 0, 0, 0);
            }
        }
    }
#undef FC1_LOAD

#pragma unroll
    for (int ni = 0; ni < 4; ni++) {
        int col = n0 + wn * 64 + ni * 16 + frow;
        float bc = bias[col];
#pragma unroll
        for (int mi = 0; mi < 4; mi++) {
            int mbase = m0 + wm * 64 + mi * 16 + (lane >> 4) * 4;
            f32x4 v = acc[mi][ni];
#pragma unroll
            for (int r = 0; r < 4; r++) {
                int m = mbase + r;
                if (m < TD_ * B_) {
                    int tt = m >> 5, bb2 = m & 31;
                    C[((size_t)bb2 * T_ + tt) * V_ + col] = v[r] + bc;
                }
            }
        }
    }
}

// ---------------------------------------------------------------------------
__global__ __launch_bounds__(256)
void argmax_kernel(const float* __restrict__ outp, float* __restrict__ preds)
{
    int row = blockIdx.x;
    int t = row >> 5, b = row & 31;
    const float* p = outp + ((size_t)b * T_ + t) * V_;
    int tid = threadIdx.x;
    float best = -3.4e38f; int bi = V_;
    for (int i = tid; i < V_; i += 256) {
        float v = p[i];
        if (v > best) { best = v; bi = i; }
    }
    __shared__ float bv[256];
    __shared__ int bidx[256];
    bv[tid] = best; bidx[tid] = bi;
    __syncthreads();
    for (int off = 128; off > 0; off >>= 1) {
        if (tid < off) {
            float v2 = bv[tid + off]; int i2 = bidx[tid + off];
            if (v2 > bv[tid] || (v2 == bv[tid] && i2 < bidx[tid])) { bv[tid] = v2; bidx[tid] = i2; }
        }
        __syncthreads();
    }
    if (tid == 0) preds[(size_t)b * T_ + t] = (float)bidx[0];
}

// ---------------------------------------------------------------------------
__global__ __launch_bounds__(256)
void zero_tail_kernel(float* __restrict__ outp, float* __restrict__ preds)
{
    int tid = blockIdx.x * 256 + threadIdx.x;
    if (tid < B_ * V_) {
        int b = tid / V_;
        int c = tid % V_;
        outp[((size_t)b * T_ + (T_ - 1)) * V_ + c] = 0.f;
    }
    if (tid < B_) preds[(size_t)tid * T_ + (T_ - 1)] = 0.f;
}

// ---------------------------------------------------------------------------
extern "C" void kernel_launch(void* const* d_in, const int* in_sizes, int n_in,
                              void* d_out, int out_size, void* d_ws, size_t ws_size,
                              hipStream_t stream)
{
    (void)in_sizes; (void)n_in; (void)out_size;
    const int*   src     = (const int*)d_in[0];
    const int*   tgt     = (const int*)d_in[1];
    const float* enc_emb = (const float*)d_in[2];
    const float* Wih_f   = (const float*)d_in[3];
    const float* Whh_f   = (const float*)d_in[4];
    const float* bih_f   = (const float*)d_in[5];
    const float* bhh_f   = (const float*)d_in[6];
    const float* Wih_b   = (const float*)d_in[7];
    const float* Whh_b   = (const float*)d_in[8];
    const float* bih_b   = (const float*)d_in[9];
    const float* bhh_b   = (const float*)d_in[10];
    const float* fcW     = (const float*)d_in[11];
    const float* fcb     = (const float*)d_in[12];
    const float* dec_emb = (const float*)d_in[13];
    const float* attn_W  = (const float*)d_in[14];
    const float* attn_b  = (const float*)d_in[15];
    const float* attn_v  = (const float*)d_in[16];
    const float* dWih    = (const float*)d_in[17];
    const float* dWhh    = (const float*)d_in[18];
    const float* dbih    = (const float*)d_in[19];
    const float* dbhh    = (const float*)d_in[20];
    const float* fc1W    = (const float*)d_in[21];
    const float* fc1b    = (const float*)d_in[22];
    (void)dbih;

    // ws layout
    float* ws     = (float*)d_ws;
    float* cat    = ws;                                  // 3,612,672 f
    float* gx_emb = cat + (size_t)TD_ * B_ * CATK_;      // 3,096,576 f
    int*   tokf   = (int*)(gx_emb + (size_t)TD_ * B_ * G3_);
    int*   tokb   = tokf + 4096;
    int*   tokd   = tokb + 4096;
    unsigned* bars = (unsigned*)(tokd + 4096);           // 4096 u (enc @0, dec @2048)
    unsigned short* Ahi = (unsigned short*)(bars + 4096);
    unsigned short* Alo = Ahi + (size_t)MPAD_ * CATK_;
    size_t ws_req = (size_t)((char*)(Alo + (size_t)MPAD_ * CATK_) - (char*)d_ws);
    const bool use_mfma = (ws_size >= ws_req);

    // d_out scratch (fully overwritten by fc1 + zero_tail afterwards)
    float* dout      = (float*)d_out;
    float* gxf       = dout;                                        // 6,291,456
    float* gxb       = gxf + (size_t)S_ * B_ * G3_;                 // 6,291,456
    float* enc_bt    = gxb + (size_t)S_ * B_ * G3_;                 // 4,194,304
    float* enc_projB = enc_bt + (size_t)B_ * S_ * 2 * H_;           // 2,097,152
    float* h_enc     = enc_projB + (size_t)B_ * S_ * H_;            // 4 x 16,384 ([dir][pp][b][k])
    float* hT        = h_enc + 4 * B_ * H_;                         // 2 x 16,384 ([pp][b][k])
    float* hwhT      = hT + 2 * B_ * H_;                            // 16,384 ([b][k])
    float* wT        = hwhT + B_ * H_;                              // 32,768 ([b][c])
    float* wpart     = wT + 2 * B_ * H_;                            // 131,072 ([b][q][1024])
    float* mlq       = wpart + (size_t)B_ * 4 * 1024;               // 256
    float* preds     = dout + (size_t)B_ * T_ * V_;

    dim3 thr(256);

    hipLaunchKernelGGL(prep_kernel, dim3(256), thr, 0, stream,
                       src, tgt, tokf, tokb, tokd, h_enc, bars);
    hipLaunchKernelGGL(emb_cat_kernel, dim3(TD_ * B_), thr, 0, stream, tokd, dec_emb, cat);

    hipLaunchKernelGGL((gemm128_kernel<1, 0>), dim3(G3_ / 128, (S_ * B_) / 128), thr, 0, stream,
                       (const float*)nullptr, 0, tokf, enc_emb, Wih_f, E_, bih_f,
                       gxf, G3_, S_ * B_, G3_, E_);
    hipLaunchKernelGGL((gemm128_kernel<1, 0>), dim3(G3_ / 128, (S_ * B_) / 128), thr, 0, stream,
                       (const float*)nullptr, 0, tokb, enc_emb, Wih_b, E_, bih_b,
                       gxb, G3_, S_ * B_, G3_, E_);

    // encoder recurrence + enc_fc in ONE launch (128 blocks, group barriers)
    hipLaunchKernelGGL(enc_coop_kernel, dim3(128), thr, 0, stream,
                       gxf, gxb, Whh_f, bhh_f, Whh_b, bhh_b, h_enc, enc_bt,
                       fcW, fcb, hT /* slot 0, [b][k] */, bars);

    hipLaunchKernelGGL((gemm128_kernel<0, 0>), dim3(H_ / 128, (B_ * S_) / 128), thr, 0, stream,
                       enc_bt, 2 * H_, (const int*)nullptr, (const float*)nullptr,
                       attn_W + H_, G3_, attn_b, enc_projB, H_, B_ * S_, H_, 2 * H_);

    hipLaunchKernelGGL((gemm128_kernel<1, 0>), dim3(G3_ / 128, (TD_ * B_ + 127) / 128), thr, 0, stream,
                       (const float*)nullptr, 0, tokd, dec_emb, dWih, DIN_, dbih,
                       gx_emb, G3_, TD_ * B_, G3_, E_);

    // decoder recurrence in ONE launch (256 blocks, group barriers)
    hipLaunchKernelGGL(dec_coop_kernel, dim3(256), thr, 0, stream,
                       attn_W, attn_v, enc_projB, enc_bt, src,
                       dWhh, dbhh, dWih, gx_emb, cat, hT, hwhT, wT, wpart, mlq,
                       bars + 2048);

    if (use_mfma) {
        hipLaunchKernelGGL(splitA_kernel, dim3((MPAD_ * CATK_ / 4 + 255) / 256), thr, 0, stream,
                           cat, Ahi, Alo);
        hipLaunchKernelGGL(fc1_mfma_kernel, dim3(MPAD_ / 128, V_ / 128), thr, 0, stream,
                           Ahi, Alo, fc1W, fc1b, dout);
    } else {
        hipLaunchKernelGGL((gemm128_kernel<0, 1>), dim3(V_ / 128, (TD_ * B_ + 127) / 128), thr, 0, stream,
                           cat, CATK_, (const int*)nullptr, (const float*)nullptr,
                           fc1W, CATK_, fc1b, dout, V_, TD_ * B_, V_, CATK_);
    }

    hipLaunchKernelGGL(argmax_kernel, dim3(TD_ * B_), thr, 0, stream, dout, preds);
    hipLaunchKernelGGL(zero_tail_kernel, dim3((B_ * V_ + 255) / 256), thr, 0, stream, dout, preds);
}

// Round 13
// 6119.098 us; speedup vs baseline: 1.2151x; 1.2151x over previous
//
#include <hip/hip_runtime.h>

#define V_ 32000
#define E_ 256
#define H_ 512
#define B_ 32
#define S_ 128
#define T_ 64
#define TD_ 63        // decoder steps (T-1)
#define G3_ 1536      // 3*H
#define CATK_ 1792    // H + E + 2H
#define DIN_ 1280     // E + 2H
#define MPAD_ 2048    // padded M for fc1 MFMA

typedef __attribute__((ext_vector_type(8))) short bf16x8;
typedef __attribute__((ext_vector_type(4))) float f32x4;

__device__ inline unsigned short bf16_rne(float x) {
    unsigned u = __float_as_uint(x);
    unsigned r = u + 0x7FFFu + ((u >> 16) & 1u);
    return (unsigned short)(r >> 16);
}

// agent-scope ops: coherence-point access, no cache invalidation (r5-proven)
__device__ __forceinline__ float ato_ldf(const float* p) {
    return __hip_atomic_load((const float*)p, __ATOMIC_RELAXED, __HIP_MEMORY_SCOPE_AGENT);
}
__device__ __forceinline__ void ato_stf(float* p, float v) {
    __hip_atomic_store(p, v, __ATOMIC_RELAXED, __HIP_MEMORY_SCOPE_AGENT);
}

// ---------------------------------------------------------------------------
// Single-level GROUP barrier: one cacheline per group (cnt @ +0, gen @ +32).
// Fence-free: data moves via agent atomics; vmcnt(0) drains stores first.
// ---------------------------------------------------------------------------
__device__ __forceinline__ void group_bar(unsigned* gbase, unsigned nb)
{
    asm volatile("s_waitcnt vmcnt(0)" ::: "memory");
    __syncthreads();
    if (threadIdx.x == 0) {
        unsigned* cnt = gbase;
        unsigned* gen = gbase + 32;
        unsigned g0 = __hip_atomic_load(gen, __ATOMIC_RELAXED, __HIP_MEMORY_SCOPE_AGENT);
        unsigned a  = __hip_atomic_fetch_add(cnt, 1u, __ATOMIC_RELAXED, __HIP_MEMORY_SCOPE_AGENT);
        if (a == nb - 1u) {
            __hip_atomic_store(cnt, 0u, __ATOMIC_RELAXED, __HIP_MEMORY_SCOPE_AGENT);
            __hip_atomic_store(gen, g0 + 1u, __ATOMIC_RELAXED, __HIP_MEMORY_SCOPE_AGENT);
        } else {
            while (__hip_atomic_load(gen, __ATOMIC_RELAXED, __HIP_MEMORY_SCOPE_AGENT) == g0)
                __builtin_amdgcn_s_sleep(1);
        }
    }
    __syncthreads();
}

// ---------------------------------------------------------------------------
// Hierarchical barrier (only for encoder's one full 128-block sync at tail)
// ---------------------------------------------------------------------------
__device__ __forceinline__ void fast_barN(unsigned* base, int idx, unsigned ngroups)
{
    asm volatile("s_waitcnt vmcnt(0)" ::: "memory");
    __syncthreads();
    if (threadIdx.x == 0) {
        unsigned* gcnt = base + (idx >> 4) * 64;
        unsigned* ggen = gcnt + 32;
        unsigned* tcnt = base + ngroups * 64;
        unsigned* tgen = tcnt + 32;
        unsigned g0 = __hip_atomic_load(ggen, __ATOMIC_RELAXED, __HIP_MEMORY_SCOPE_AGENT);
        unsigned a  = __hip_atomic_fetch_add(gcnt, 1u, __ATOMIC_RELAXED, __HIP_MEMORY_SCOPE_AGENT);
        if (a == 15u) {
            unsigned t0 = __hip_atomic_load(tgen, __ATOMIC_RELAXED, __HIP_MEMORY_SCOPE_AGENT);
            unsigned ta = __hip_atomic_fetch_add(tcnt, 1u, __ATOMIC_RELAXED, __HIP_MEMORY_SCOPE_AGENT);
            if (ta == ngroups - 1u) {
                __hip_atomic_store(tcnt, 0u, __ATOMIC_RELAXED, __HIP_MEMORY_SCOPE_AGENT);
                __hip_atomic_store(tgen, t0 + 1u, __ATOMIC_RELAXED, __HIP_MEMORY_SCOPE_AGENT);
            } else {
                while (__hip_atomic_load(tgen, __ATOMIC_RELAXED, __HIP_MEMORY_SCOPE_AGENT) == t0)
                    __builtin_amdgcn_s_sleep(1);
            }
            __hip_atomic_store(gcnt, 0u, __ATOMIC_RELAXED, __HIP_MEMORY_SCOPE_AGENT);
            __hip_atomic_store(ggen, g0 + 1u, __ATOMIC_RELAXED, __HIP_MEMORY_SCOPE_AGENT);
        } else {
            while (__hip_atomic_load(ggen, __ATOMIC_RELAXED, __HIP_MEMORY_SCOPE_AGENT) == g0)
                __builtin_amdgcn_s_sleep(1);
        }
    }
    __syncthreads();
}

// ---------------------------------------------------------------------------
__global__ __launch_bounds__(256)
void prep_kernel(const int* __restrict__ src, const int* __restrict__ tgt,
                 int* __restrict__ tokf, int* __restrict__ tokb, int* __restrict__ tokd,
                 float* __restrict__ enc_h0, unsigned* __restrict__ bars)
{
    int tid = blockIdx.x * 256 + threadIdx.x;
    if (tid < S_ * B_) {
        int s = tid >> 5, b = tid & 31;
        tokf[tid] = src[b * S_ + s];
        tokb[tid] = src[b * S_ + (S_ - 1 - s)];
    }
    if (tid < TD_ * B_) {
        int t = tid >> 5, b = tid & 31;
        tokd[tid] = tgt[b * T_ + t];
    }
    if (tid < 2 * B_ * H_) enc_h0[tid] = 0.f;   // encrot slot 0
    if (tid < 4096) bars[tid] = 0u;
}

// ---------------------------------------------------------------------------
__global__ __launch_bounds__(256)
void emb_cat_kernel(const int* __restrict__ tokd, const float* __restrict__ dec_emb,
                    float* __restrict__ cat)
{
    int row = blockIdx.x;          // row = t*32 + b
    int tid = threadIdx.x;         // 0..255 == E_
    cat[(size_t)row * CATK_ + H_ + tid] = dec_emb[(size_t)tokd[row] * E_ + tid];
}

// ---------------------------------------------------------------------------
// Generic fp32 GEMM (small GEMMs + fallback fc1)
// ---------------------------------------------------------------------------
template<int GATHER, int FC1MAP>
__global__ __launch_bounds__(256)
void gemm128_kernel(const float* __restrict__ A, int lda,
                    const int* __restrict__ tokens, const float* __restrict__ emb,
                    const float* __restrict__ W, int ldw,
                    const float* __restrict__ bias,
                    float* __restrict__ C, int ldc,
                    int M, int N, int K)
{
    __shared__ float As[16][132];
    __shared__ float Ws[16][132];
    (void)N;
    int tid = threadIdx.x;
    int m0 = blockIdx.y * 128, n0 = blockIdx.x * 128;
    int tx = tid & 15, ty = tid >> 4;
    float c[8][8];
#pragma unroll
    for (int i = 0; i < 8; i++)
#pragma unroll
        for (int j = 0; j < 8; j++) c[i][j] = 0.f;

    int arow = tid >> 1;
    int kq = (tid & 1) * 8;

    int am = m0 + arow; if (am >= M) am = M - 1;
    const float* arp;
    if (GATHER) arp = emb + (size_t)tokens[am] * (size_t)K;
    else        arp = A + (size_t)am * (size_t)lda;
    const float* wrp = W + (size_t)(n0 + arow) * (size_t)ldw;

    for (int kb = 0; kb < K; kb += 16) {
        __syncthreads();
        float4 a0 = *(const float4*)(arp + kb + kq);
        float4 a1 = *(const float4*)(arp + kb + kq + 4);
        float4 w0 = *(const float4*)(wrp + kb + kq);
        float4 w1 = *(const float4*)(wrp + kb + kq + 4);
        As[kq + 0][arow] = a0.x; As[kq + 1][arow] = a0.y;
        As[kq + 2][arow] = a0.z; As[kq + 3][arow] = a0.w;
        As[kq + 4][arow] = a1.x; As[kq + 5][arow] = a1.y;
        As[kq + 6][arow] = a1.z; As[kq + 7][arow] = a1.w;
        Ws[kq + 0][arow] = w0.x; Ws[kq + 1][arow] = w0.y;
        Ws[kq + 2][arow] = w0.z; Ws[kq + 3][arow] = w0.w;
        Ws[kq + 4][arow] = w1.x; Ws[kq + 5][arow] = w1.y;
        Ws[kq + 6][arow] = w1.z; Ws[kq + 7][arow] = w1.w;
        __syncthreads();
#pragma unroll
        for (int kk = 0; kk < 16; kk++) {
            float a[8], bb[8];
            *(float4*)&a[0]  = *(const float4*)&As[kk][ty * 8];
            *(float4*)&a[4]  = *(const float4*)&As[kk][ty * 8 + 4];
            *(float4*)&bb[0] = *(const float4*)&Ws[kk][tx * 8];
            *(float4*)&bb[4] = *(const float4*)&Ws[kk][tx * 8 + 4];
#pragma unroll
            for (int i = 0; i < 8; i++)
#pragma unroll
                for (int j = 0; j < 8; j++) c[i][j] += a[i] * bb[j];
        }
    }

#pragma unroll
    for (int i = 0; i < 8; i++) {
        int m = m0 + ty * 8 + i;
        if (m < M) {
            size_t rowoff;
            if (FC1MAP) { int tt = m >> 5, bb2 = m & 31; rowoff = ((size_t)bb2 * T_ + tt) * (size_t)ldc; }
            else        rowoff = (size_t)m * (size_t)ldc;
#pragma unroll
            for (int j = 0; j < 8; j += 4) {
                int n = n0 + tx * 8 + j;
                float4 v;
                v.x = c[i][j + 0] + bias[n + 0];
                v.y = c[i][j + 1] + bias[n + 1];
                v.z = c[i][j + 2] + bias[n + 2];
                v.w = c[i][j + 3] + bias[n + 3];
                *(float4*)(C + rowoff + n) = v;
            }
        }
    }
}

// ---------------------------------------------------------------------------
// PERSISTENT bi-GRU encoder (r8-exact work layout, L2-resident weights):
// rotating h (cached reads, agent stores). Per-step barrier narrowed to the
// true producer set: (dir,bh) group of 32 blocks, single-level.
// Tail (after one full barrier): enc_fc -> hT0 [b][k].
// ---------------------------------------------------------------------------
__global__ __launch_bounds__(256)
void enc_coop_kernel(const float* __restrict__ gxf, const float* __restrict__ gxb,
                     const float* __restrict__ Whh_f, const float* __restrict__ bhh_f,
                     const float* __restrict__ Whh_b, const float* __restrict__ bhh_b,
                     float* __restrict__ encrot, float* __restrict__ enc_bt,
                     const float* __restrict__ fcW, const float* __restrict__ fcb,
                     float* __restrict__ hT0, unsigned* __restrict__ bars)
{
    const int bid = blockIdx.x;
    const int dir = bid >> 6, bh = (bid >> 5) & 1, kc = bid & 31;
    const int tid = threadIdx.x;
    const int bl = tid & 15, kl = tid >> 4;
    const int b = bh * 16 + bl, k = kc * 16 + kl;
    const float* Whh = dir ? Whh_b : Whh_f;
    const float* bhhp = dir ? bhh_b : bhh_f;
    const float* gx  = dir ? gxb : gxf;
    __shared__ float hL[16 * 516];
    const float* wr = Whh + (size_t)k * H_;
    const float* wz = Whh + (size_t)(H_ + k) * H_;
    const float* wn = Whh + (size_t)(2 * H_ + k) * H_;
    const float b_r = bhhp[k], b_z = bhhp[H_ + k], b_n = bhhp[2 * H_ + k];
    unsigned* gbar = bars + (dir * 2 + bh) * 64;   // 32-block producer group

    for (int t = 0; t < S_; ++t) {
        const float* hin = encrot + (size_t)t * (2 * B_ * H_) + (size_t)dir * (B_ * H_);
        float* hout = encrot + (size_t)(t + 1) * (2 * B_ * H_) + (size_t)dir * (B_ * H_);
        const float* hsrc = hin + (size_t)bh * 16 * H_;
        for (int i = tid * 4; i < 16 * H_; i += 1024) {
            int r = i >> 9, cix = i & 511;
            *(float4*)&hL[r * 516 + cix] = *(const float4*)(hsrc + i);
        }
        __syncthreads();
        float ar = 0.f, az = 0.f, an = 0.f;
        const float* hv = &hL[bl * 516];
#pragma unroll 4
        for (int j = 0; j < H_; j += 4) {
            float4 h4 = *(const float4*)(hv + j);
            float4 r4 = *(const float4*)(wr + j);
            float4 z4 = *(const float4*)(wz + j);
            float4 n4 = *(const float4*)(wn + j);
            ar += h4.x * r4.x + h4.y * r4.y + h4.z * r4.z + h4.w * r4.w;
            az += h4.x * z4.x + h4.y * z4.y + h4.z * z4.z + h4.w * z4.w;
            an += h4.x * n4.x + h4.y * n4.y + h4.z * n4.z + h4.w * n4.w;
        }
        const float* gxr = gx + ((size_t)t * B_ + b) * G3_;
        float xr = gxr[k], xz = gxr[H_ + k], xn = gxr[2 * H_ + k];
        float rg = 1.f / (1.f + expf(-(xr + ar + b_r)));
        float zg = 1.f / (1.f + expf(-(xz + az + b_z)));
        float ng = tanhf(xn + rg * (an + b_n));
        float hp = hL[bl * 516 + k];
        float h2 = (1.f - zg) * ng + zg * hp;
        ato_stf(hout + (size_t)b * H_ + k, h2);
        int s_out = dir ? (S_ - 1 - t) : t;
        enc_bt[((size_t)b * S_ + s_out) * (2 * H_) + dir * H_ + k] = h2;
        group_bar(gbar, 32);
    }
    fast_barN(bars + 1024, bid, 8);    // both dirs done

    // tail: hidden = tanh([hf,hb] @ fcW.T + fcb) -> hT0[b][k]
    {
        const int b2 = bid & 31, ih = bid >> 5;
        float* hc = hL;
        const float* hfin = encrot + (size_t)S_ * (2 * B_ * H_);
        const float* hf  = hfin + (size_t)b2 * H_;
        const float* hbk = hfin + (size_t)B_ * H_ + (size_t)b2 * H_;
        for (int i = tid; i < H_; i += 256) { hc[i] = hf[i]; hc[H_ + i] = hbk[i]; }
        __syncthreads();
        if (tid < 128) {
            int i = ih * 128 + tid;
            const float* w = fcW + (size_t)i * (2 * H_);
            float acc = 0.f;
            for (int j = 0; j < 2 * H_; j += 4) {
                float4 a4 = *(const float4*)&hc[j];
                float4 w4 = *(const float4*)(w + j);
                acc += a4.x * w4.x + a4.y * w4.y + a4.z * w4.z + a4.w * w4.w;
            }
            ato_stf(hT0 + (size_t)b2 * H_ + i, tanhf(acc + fcb[i]));
        }
    }
}

// ---------------------------------------------------------------------------
// PERSISTENT attention decoder v13: 256 blocks = (b 32) x (sq 8).
// Block owns batch b, s-slice [sq*16,+16), k-slice [sq*64,+64).
// Attention data is REGISTER-RESIDENT (constant over t):
//   projreg[32] = enc_projB slice for (s = s0+tid>>4, chunk tid&15)
//   ebtreg[16][4] = enc_bt slice cols tid*4..+3 for own 16 s
// -> zero per-step global streaming for attention. Weights k-sliced,
// sq=bid%8 -> XCD: 1.3 MB distinct/XCD, L2-resident.
// Phases: P0 h->hwh(global)+ghh(LDS) | P1 scores+partial-softmax+wpart |
//         P2 combine->w(LDS)+xw+gates. 3x 8-block group barriers/step.
// ---------------------------------------------------------------------------
__global__ __launch_bounds__(256)
void dec_coop_kernel(const float* __restrict__ attn_W, const float* __restrict__ attn_v,
                     const float* __restrict__ enc_projB, const float* __restrict__ enc_bt,
                     const int* __restrict__ src,
                     const float* __restrict__ dWhh, const float* __restrict__ dbhh,
                     const float* __restrict__ dWih, const float* __restrict__ gx_emb,
                     float* __restrict__ cat, float* __restrict__ hT,
                     float* __restrict__ hwhT, float* __restrict__ wpart,
                     float* __restrict__ mlq, unsigned* __restrict__ bars)
{
    const int bid = blockIdx.x, tid = threadIdx.x;
    const int b = bid >> 3, sq = bid & 7;
    const int k0 = sq * 64, s0 = sq * 16;
    __shared__ float hA[512], hwhL[512], vL[512];
    __shared__ float ghhL[192], xwL[192], wL[1024];
    __shared__ float sLq[16], eSq[16], cmbL[16];
    unsigned* gbar = bars + 2048 + b * 64;

    const int ps = tid >> 4, pu = tid & 15;
    // ---- constant register slices (loaded once) ----
    float projreg[32];
    {
        const float* pr = enc_projB + ((size_t)b * S_ + s0 + ps) * H_ + pu * 32;
#pragma unroll
        for (int i = 0; i < 32; i += 4) {
            float4 v = *(const float4*)(pr + i);
            projreg[i] = v.x; projreg[i + 1] = v.y; projreg[i + 2] = v.z; projreg[i + 3] = v.w;
        }
    }
    float ebtreg[16][4];
    {
        const int c4 = tid * 4;
#pragma unroll
        for (int s = 0; s < 16; s++) {
            float4 v = *(const float4*)(enc_bt + ((size_t)b * S_ + s0 + s) * (2 * H_) + c4);
            ebtreg[s][0] = v.x; ebtreg[s][1] = v.y; ebtreg[s][2] = v.z; ebtreg[s][3] = v.w;
        }
    }
    for (int i = tid; i < H_; i += 256) vL[i] = attn_v[i];
    const int msk = (src[b * S_ + s0 + ps] != 0);

    // P0 row task (constant across steps)
    const float* w0row;
    float bias0 = 0.f;
    if (tid < 64) w0row = attn_W + (size_t)(k0 + tid) * G3_;
    else {
        int rr = tid - 64;
        int grow = (rr >> 6) * H_ + k0 + (rr & 63);
        w0row = dWhh + (size_t)grow * H_;
        bias0 = dbhh[grow];
    }

    for (int t = 0; t < TD_; ++t) {
        const int pp = t & 1;
        const float* hin = hT + (size_t)pp * (B_ * H_);
        float* hout = hT + (size_t)(1 - pp) * (B_ * H_);
        float* cat_t = cat + (size_t)t * B_ * CATK_;

        // ---- P0: h[b] -> hwh (64 rows, global) + ghh (192 rows, LDS) ----
        for (int j = tid; j < H_; j += 256) hA[j] = ato_ldf(hin + (size_t)b * H_ + j);
        __syncthreads();
        {
            float a0 = 0.f, a1 = 0.f;
            for (int j = 0; j < H_; j += 8) {
                float4 w0 = *(const float4*)(w0row + j);
                float4 w1 = *(const float4*)(w0row + j + 4);
                float4 h0 = *(const float4*)&hA[j];
                float4 h1 = *(const float4*)&hA[j + 4];
                a0 += w0.x * h0.x + w0.y * h0.y + w0.z * h0.z + w0.w * h0.w;
                a1 += w1.x * h1.x + w1.y * h1.y + w1.z * h1.z + w1.w * h1.w;
            }
            float acc = a0 + a1;
            if (tid < 64) ato_stf(hwhT + (size_t)b * H_ + k0 + tid, acc);
            else ghhL[tid - 64] = acc + bias0;
        }
        group_bar(gbar, 8);

        // ---- P1: scores (reg-resident proj) + local softmax + partial w ----
        for (int i = tid; i < H_; i += 256) hwhL[i] = ato_ldf(hwhT + (size_t)b * H_ + i);
        __syncthreads();
        {
            float acc = 0.f;
#pragma unroll
            for (int i = 0; i < 32; i++) {
                int e = pu * 32 + i;
                float x = hwhL[e] + projreg[i];
                float e2 = __expf(2.f * x);
                acc += vL[e] * (1.f - 2.f / (e2 + 1.f));
            }
            acc += __shfl_xor(acc, 1);
            acc += __shfl_xor(acc, 2);
            acc += __shfl_xor(acc, 4);
            acc += __shfl_xor(acc, 8);
            if (pu == 0) sLq[ps] = msk ? acc : -1e10f;
        }
        __syncthreads();
        if (tid < 16) {
            float v = sLq[tid];
            float m = v;
#pragma unroll
            for (int off = 1; off < 16; off <<= 1) m = fmaxf(m, __shfl_xor(m, off));
            float e = expf(v - m);
            eSq[tid] = e;
            float l = e;
#pragma unroll
            for (int off = 1; off < 16; off <<= 1) l += __shfl_xor(l, off);
            if (tid == 0) {
                ato_stf(mlq + (size_t)(b * 8 + sq) * 2 + 0, m);
                ato_stf(mlq + (size_t)(b * 8 + sq) * 2 + 1, l);
            }
        }
        __syncthreads();
        {
            float x0 = 0.f, x1 = 0.f, x2 = 0.f, x3 = 0.f;
#pragma unroll
            for (int s = 0; s < 16; s++) {
                float es = eSq[s];
                x0 += es * ebtreg[s][0]; x1 += es * ebtreg[s][1];
                x2 += es * ebtreg[s][2]; x3 += es * ebtreg[s][3];
            }
            float* dst = wpart + (size_t)(b * 8 + sq) * 1024 + tid * 4;
            ato_stf(dst + 0, x0); ato_stf(dst + 1, x1);
            ato_stf(dst + 2, x2); ato_stf(dst + 3, x3);
        }
        group_bar(gbar, 8);

        // ---- P2: combine -> w (LDS) -> xw -> gates -> h' + cat ----
        if (tid < 16) cmbL[tid] = ato_ldf(mlq + (size_t)(b * 8 + (tid >> 1)) * 2 + (tid & 1));
        __syncthreads();
        {
            float m = cmbL[0];
#pragma unroll
            for (int q = 1; q < 8; q++) m = fmaxf(m, cmbL[2 * q]);
            float eq[8]; float L = 0.f;
#pragma unroll
            for (int q = 0; q < 8; q++) { eq[q] = expf(cmbL[2 * q] - m); L += eq[q] * cmbL[2 * q + 1]; }
            float inv = 1.f / L;
            int c4 = tid * 4;
            float w0 = 0.f, w1 = 0.f, w2 = 0.f, w3 = 0.f;
#pragma unroll
            for (int q = 0; q < 8; q++) {
                const float* p = wpart + (size_t)(b * 8 + q) * 1024 + c4;
                float e = eq[q];
                w0 += e * ato_ldf(p + 0); w1 += e * ato_ldf(p + 1);
                w2 += e * ato_ldf(p + 2); w3 += e * ato_ldf(p + 3);
            }
            w0 *= inv; w1 *= inv; w2 *= inv; w3 *= inv;
            wL[c4 + 0] = w0; wL[c4 + 1] = w1; wL[c4 + 2] = w2; wL[c4 + 3] = w3;
            if (sq == 0) {
                float4 o; o.x = w0; o.y = w1; o.z = w2; o.w = w3;
                *(float4*)(cat_t + (size_t)b * CATK_ + (H_ + E_) + c4) = o;
            }
        }
        __syncthreads();
        if (tid < 192) {
            int grow = (tid >> 6) * H_ + k0 + (tid & 63);
            const float* wrow = dWih + (size_t)grow * DIN_ + E_;
            float a0 = 0.f, a1 = 0.f;
            for (int c = 0; c < 2 * H_; c += 8) {
                float4 w0 = *(const float4*)(wrow + c);
                float4 w1 = *(const float4*)(wrow + c + 4);
                float4 x0 = *(const float4*)&wL[c];
                float4 x1 = *(const float4*)&wL[c + 4];
                a0 += w0.x * x0.x + w0.y * x0.y + w0.z * x0.z + w0.w * x0.w;
                a1 += w1.x * x1.x + w1.y * x1.y + w1.z * x1.z + w1.w * x1.w;
            }
            xwL[tid] = a0 + a1;
        }
        __syncthreads();
        if (tid < 64) {
            int k = k0 + tid;
            float hr = ghhL[tid], hz = ghhL[64 + tid], hn = ghhL[128 + tid];
            float xr = xwL[tid], xz = xwL[64 + tid], xn = xwL[128 + tid];
            const float* gxe = gx_emb + ((size_t)t * B_ + b) * G3_;
            float rg = 1.f / (1.f + expf(-(gxe[k] + xr + hr)));
            float zg = 1.f / (1.f + expf(-(gxe[H_ + k] + xz + hz)));
            float ng = tanhf(gxe[2 * H_ + k] + xn + rg * hn);
            float hp = hA[k];
            float h2 = (1.f - zg) * ng + zg * hp;
            ato_stf(hout + (size_t)b * H_ + k, h2);
            cat_t[(size_t)b * CATK_ + k] = h2;
        }
        group_bar(gbar, 8);
    }
}

// ---------------------------------------------------------------------------
__global__ __launch_bounds__(256)
void splitA_kernel(const float* __restrict__ cat,
                   unsigned short* __restrict__ Ahi, unsigned short* __restrict__ Alo)
{
    size_t i4 = ((size_t)blockIdx.x * 256 + threadIdx.x) * 4;
    if (i4 >= (size_t)MPAD_ * CATK_) return;
    size_t row = i4 / CATK_;
    float4 v;
    if (row < (size_t)TD_ * B_) v = *(const float4*)(cat + i4);
    else { v.x = v.y = v.z = v.w = 0.f; }
    float f[4] = {v.x, v.y, v.z, v.w};
    unsigned short h[4], l[4];
#pragma unroll
    for (int j = 0; j < 4; j++) {
        h[j] = bf16_rne(f[j]);
        float hf = __uint_as_float((unsigned)h[j] << 16);
        l[j] = bf16_rne(f[j] - hf);
    }
    *(ushort4*)(Ahi + i4) = make_ushort4(h[0], h[1], h[2], h[3]);
    *(ushort4*)(Alo + i4) = make_ushort4(l[0], l[1], l[2], l[3]);
}

// ---------------------------------------------------------------------------
__global__ __launch_bounds__(256)
void fc1_mfma_kernel(const unsigned short* __restrict__ Ahi,
                     const unsigned short* __restrict__ Alo,
                     const float* __restrict__ W,
                     const float* __restrict__ bias,
                     float* __restrict__ C)
{
    __shared__ unsigned short lA[2][128][40];
    __shared__ unsigned short lW[2][128][40];
    const int tid = threadIdx.x;
    const int m0 = blockIdx.x * 128, n0 = blockIdx.y * 128;
    const int w = tid >> 6, lane = tid & 63;
    const int wm = w >> 1, wn = w & 1;
    const int frow = lane & 15, fk = (lane >> 4) * 8;

    f32x4 acc[4][4];
#pragma unroll
    for (int mi = 0; mi < 4; mi++)
#pragma unroll
        for (int ni = 0; ni < 4; ni++) acc[mi][ni] = (f32x4){0.f, 0.f, 0.f, 0.f};

    const int srow = tid >> 1;
    const int skq = (tid & 1) * 16;

    const unsigned short* gAhi = Ahi + (size_t)(m0 + srow) * CATK_ + skq;
    const unsigned short* gAlo = Alo + (size_t)(m0 + srow) * CATK_ + skq;
    const float*          gW   = W   + (size_t)(n0 + srow) * CATK_ + skq;

    int4 rAh0, rAh1, rAl0, rAl1;
    float4 rW0, rW1, rW2, rW3;

#define FC1_LOAD(kb)                                        \
    do {                                                    \
        rAh0 = *(const int4*)(gAhi + (kb));                 \
        rAh1 = *(const int4*)(gAhi + (kb) + 8);             \
        rAl0 = *(const int4*)(gAlo + (kb));                 \
        rAl1 = *(const int4*)(gAlo + (kb) + 8);             \
        rW0  = *(const float4*)(gW + (kb));                 \
        rW1  = *(const float4*)(gW + (kb) + 4);             \
        rW2  = *(const float4*)(gW + (kb) + 8);             \
        rW3  = *(const float4*)(gW + (kb) + 12);            \
    } while (0)

    FC1_LOAD(0);

    for (int kb = 0; kb < CATK_; kb += 32) {
        __syncthreads();
        *(int4*)&lA[0][srow][skq]     = rAh0;
        *(int4*)&lA[0][srow][skq + 8] = rAh1;
        *(int4*)&lA[1][srow][skq]     = rAl0;
        *(int4*)&lA[1][srow][skq + 8] = rAl1;
        {
            float f[16] = {rW0.x, rW0.y, rW0.z, rW0.w, rW1.x, rW1.y, rW1.z, rW1.w,
                           rW2.x, rW2.y, rW2.z, rW2.w, rW3.x, rW3.y, rW3.z, rW3.w};
            unsigned hp[8], lp[8];
#pragma unroll
            for (int j = 0; j < 8; j++) {
                float x0 = f[2 * j], x1 = f[2 * j + 1];
                unsigned short h0 = bf16_rne(x0), h1 = bf16_rne(x1);
                float r0 = x0 - __uint_as_float((unsigned)h0 << 16);
                float r1 = x1 - __uint_as_float((unsigned)h1 << 16);
                hp[j] = (unsigned)h0 | ((unsigned)h1 << 16);
                lp[j] = (unsigned)bf16_rne(r0) | ((unsigned)bf16_rne(r1) << 16);
            }
            *(int4*)&lW[0][srow][skq]     = make_int4(hp[0], hp[1], hp[2], hp[3]);
            *(int4*)&lW[0][srow][skq + 8] = make_int4(hp[4], hp[5], hp[6], hp[7]);
            *(int4*)&lW[1][srow][skq]     = make_int4(lp[0], lp[1], lp[2], lp[3]);
            *(int4*)&lW[1][srow][skq + 8] = make_int4(lp[4], lp[5], lp[6], lp[7]);
        }
        __syncthreads();
        if (kb + 32 < CATK_) FC1_LOAD(kb + 32);

        bf16x8 a[2][4];
#pragma unroll
        for (int mi = 0; mi < 4; mi++) {
            int r = wm * 64 + mi * 16 + frow;
            a[0][mi] = *(const bf16x8*)&lA[0][r][fk];
            a[1][mi] = *(const bf16x8*)&lA[1][r][fk];
        }
#pragma unroll
        for (int ni = 0; ni < 4; ni++) {
            int r = wn * 64 + ni * 16 + frow;
            bf16x8 bh = *(const bf16x8*)&lW[0][r][fk];
            bf16x8 bl = *(const bf16x8*)&lW[1][r][fk];
#pragma unroll
            for (int mi = 0; mi < 4; mi++) {
                acc[mi][ni] = __builtin_amdgcn_mfma_f32_16x16x32_bf16(a[0][mi], bh, acc[mi][ni], 0, 0, 0);
                acc[mi][ni] = __builtin_amdgcn_mfma_f32_16x16x32_bf16(a[1][mi], bh, acc[mi][ni], 0, 0, 0);
                acc[mi][ni] = __builtin_amdgcn_mfma_f32_16x16x32_bf16(a[0][mi], bl, acc[mi][ni], 0, 0, 0);
            }
        }
    }
#undef FC1_LOAD

#pragma unroll
    for (int ni = 0; ni < 4; ni++) {
        int col = n0 + wn * 64 + ni * 16 + frow;
        float bc = bias[col];
#pragma unroll
        for (int mi = 0; mi < 4; mi++) {
            int mbase = m0 + wm * 64 + mi * 16 + (lane >> 4) * 4;
            f32x4 v = acc[mi][ni];
#pragma unroll
            for (int r = 0; r < 4; r++) {
                int m = mbase + r;
                if (m < TD_ * B_) {
                    int tt = m >> 5, bb2 = m & 31;
                    C[((size_t)bb2 * T_ + tt) * V_ + col] = v[r] + bc;
                }
            }
        }
    }
}

// ---------------------------------------------------------------------------
__global__ __launch_bounds__(256)
void argmax_kernel(const float* __restrict__ outp, float* __restrict__ preds)
{
    int row = blockIdx.x;
    int t = row >> 5, b = row & 31;
    const float* p = outp + ((size_t)b * T_ + t) * V_;
    int tid = threadIdx.x;
    float best = -3.4e38f; int bi = V_;
    for (int i = tid; i < V_; i += 256) {
        float v = p[i];
        if (v > best) { best = v; bi = i; }
    }
    __shared__ float bv[256];
    __shared__ int bidx[256];
    bv[tid] = best; bidx[tid] = bi;
    __syncthreads();
    for (int off = 128; off > 0; off >>= 1) {
        if (tid < off) {
            float v2 = bv[tid + off]; int i2 = bidx[tid + off];
            if (v2 > bv[tid] || (v2 == bv[tid] && i2 < bidx[tid])) { bv[tid] = v2; bidx[tid] = i2; }
        }
        __syncthreads();
    }
    if (tid == 0) preds[(size_t)b * T_ + t] = (float)bidx[0];
}

// ---------------------------------------------------------------------------
__global__ __launch_bounds__(256)
void zero_tail_kernel(float* __restrict__ outp, float* __restrict__ preds)
{
    int tid = blockIdx.x * 256 + threadIdx.x;
    if (tid < B_ * V_) {
        int b = tid / V_;
        int c = tid % V_;
        outp[((size_t)b * T_ + (T_ - 1)) * V_ + c] = 0.f;
    }
    if (tid < B_) preds[(size_t)tid * T_ + (T_ - 1)] = 0.f;
}

// ---------------------------------------------------------------------------
extern "C" void kernel_launch(void* const* d_in, const int* in_sizes, int n_in,
                              void* d_out, int out_size, void* d_ws, size_t ws_size,
                              hipStream_t stream)
{
    (void)in_sizes; (void)n_in; (void)out_size;
    const int*   src     = (const int*)d_in[0];
    const int*   tgt     = (const int*)d_in[1];
    const float* enc_emb = (const float*)d_in[2];
    const float* Wih_f   = (const float*)d_in[3];
    const float* Whh_f   = (const float*)d_in[4];
    const float* bih_f   = (const float*)d_in[5];
    const float* bhh_f   = (const float*)d_in[6];
    const float* Wih_b   = (const float*)d_in[7];
    const float* Whh_b   = (const float*)d_in[8];
    const float* bih_b   = (const float*)d_in[9];
    const float* bhh_b   = (const float*)d_in[10];
    const float* fcW     = (const float*)d_in[11];
    const float* fcb     = (const float*)d_in[12];
    const float* dec_emb = (const float*)d_in[13];
    const float* attn_W  = (const float*)d_in[14];
    const float* attn_b  = (const float*)d_in[15];
    const float* attn_v  = (const float*)d_in[16];
    const float* dWih    = (const float*)d_in[17];
    const float* dWhh    = (const float*)d_in[18];
    const float* dbih    = (const float*)d_in[19];
    const float* dbhh    = (const float*)d_in[20];
    const float* fc1W    = (const float*)d_in[21];
    const float* fc1b    = (const float*)d_in[22];
    (void)dbih;

    // ws layout
    float* ws     = (float*)d_ws;
    float* cat    = ws;                                  // 3,612,672 f
    float* gx_emb = cat + (size_t)TD_ * B_ * CATK_;      // 3,096,576 f
    int*   tokf   = (int*)(gx_emb + (size_t)TD_ * B_ * G3_);
    int*   tokb   = tokf + 4096;
    int*   tokd   = tokb + 4096;
    unsigned* bars = (unsigned*)(tokd + 4096);           // 4096 u: enc grp 0..255,
                                                         // enc full @1024, dec @2048
    unsigned short* Ahi = (unsigned short*)(bars + 4096);
    unsigned short* Alo = Ahi + (size_t)MPAD_ * CATK_;
    size_t ws_req = (size_t)((char*)(Alo + (size_t)MPAD_ * CATK_) - (char*)d_ws);
    const bool use_mfma = (ws_size >= ws_req);

    // d_out scratch (fully overwritten by fc1 + zero_tail afterwards)
    float* dout      = (float*)d_out;
    float* gxf       = dout;                                        // 6,291,456
    float* gxb       = gxf + (size_t)S_ * B_ * G3_;                 // 6,291,456
    float* enc_bt    = gxb + (size_t)S_ * B_ * G3_;                 // 4,194,304
    float* enc_projB = enc_bt + (size_t)B_ * S_ * 2 * H_;           // 2,097,152
    float* encrot    = enc_projB + (size_t)B_ * S_ * H_;            // 129 x 32,768
    float* hT        = encrot + (size_t)(S_ + 1) * 2 * B_ * H_;     // 2 x 16,384 ([pp][b][k])
    float* hwhT      = hT + 2 * B_ * H_;                            // 16,384 ([b][k])
    float* wpart     = hwhT + B_ * H_;                              // 262,144 ([b][q8][1024])
    float* mlq       = wpart + (size_t)B_ * 8 * 1024;               // 512
    float* preds     = dout + (size_t)B_ * T_ * V_;

    dim3 thr(256);

    hipLaunchKernelGGL(prep_kernel, dim3(256), thr, 0, stream,
                       src, tgt, tokf, tokb, tokd, encrot, bars);
    hipLaunchKernelGGL(emb_cat_kernel, dim3(TD_ * B_), thr, 0, stream, tokd, dec_emb, cat);

    hipLaunchKernelGGL((gemm128_kernel<1, 0>), dim3(G3_ / 128, (S_ * B_) / 128), thr, 0, stream,
                       (const float*)nullptr, 0, tokf, enc_emb, Wih_f, E_, bih_f,
                       gxf, G3_, S_ * B_, G3_, E_);
    hipLaunchKernelGGL((gemm128_kernel<1, 0>), dim3(G3_ / 128, (S_ * B_) / 128), thr, 0, stream,
                       (const float*)nullptr, 0, tokb, enc_emb, Wih_b, E_, bih_b,
                       gxb, G3_, S_ * B_, G3_, E_);

    // encoder recurrence + enc_fc in ONE launch (128 blocks, 32-block groups)
    hipLaunchKernelGGL(enc_coop_kernel, dim3(128), thr, 0, stream,
                       gxf, gxb, Whh_f, bhh_f, Whh_b, bhh_b, encrot, enc_bt,
                       fcW, fcb, hT /* slot 0, [b][k] */, bars);

    hipLaunchKernelGGL((gemm128_kernel<0, 0>), dim3(H_ / 128, (B_ * S_) / 128), thr, 0, stream,
                       enc_bt, 2 * H_, (const int*)nullptr, (const float*)nullptr,
                       attn_W + H_, G3_, attn_b, enc_projB, H_, B_ * S_, H_, 2 * H_);

    hipLaunchKernelGGL((gemm128_kernel<1, 0>), dim3(G3_ / 128, (TD_ * B_ + 127) / 128), thr, 0, stream,
                       (const float*)nullptr, 0, tokd, dec_emb, dWih, DIN_, dbih,
                       gx_emb, G3_, TD_ * B_, G3_, E_);

    // decoder recurrence in ONE launch (256 blocks, reg-resident attention)
    hipLaunchKernelGGL(dec_coop_kernel, dim3(256), thr, 0, stream,
                       attn_W, attn_v, enc_projB, enc_bt, src,
                       dWhh, dbhh, dWih, gx_emb, cat, hT, hwhT, wpart, mlq,
                       bars);

    if (use_mfma) {
        hipLaunchKernelGGL(splitA_kernel, dim3((MPAD_ * CATK_ / 4 + 255) / 256), thr, 0, stream,
                           cat, Ahi, Alo);
        hipLaunchKernelGGL(fc1_mfma_kernel, dim3(MPAD_ / 128, V_ / 128), thr, 0, stream,
                           Ahi, Alo, fc1W, fc1b, dout);
    } else {
        hipLaunchKernelGGL((gemm128_kernel<0, 1>), dim3(V_ / 128, (TD_ * B_ + 127) / 128), thr, 0, stream,
                           cat, CATK_, (const int*)nullptr, (const float*)nullptr,
                           fc1W, CATK_, fc1b, dout, V_, TD_ * B_, V_, CATK_);
    }

    hipLaunchKernelGGL(argmax_kernel, dim3(TD_ * B_), thr, 0, stream, dout, preds);
    hipLaunchKernelGGL(zero_tail_kernel, dim3((B_ * V_ + 255) / 256), thr, 0, stream, dout, preds);
}

// Round 14
// 6042.257 us; speedup vs baseline: 1.2305x; 1.0127x over previous
//
#include <hip/hip_runtime.h>

#define V_ 32000
#define E_ 256
#define H_ 512
#define B_ 32
#define S_ 128
#define T_ 64
#define TD_ 63        // decoder steps (T-1)
#define G3_ 1536      // 3*H
#define CATK_ 1792    // H + E + 2H
#define DIN_ 1280     // E + 2H
#define MPAD_ 2048    // padded M for fc1 MFMA

typedef __attribute__((ext_vector_type(8))) short bf16x8;
typedef __attribute__((ext_vector_type(4))) float f32x4;

__device__ inline unsigned short bf16_rne(float x) {
    unsigned u = __float_as_uint(x);
    unsigned r = u + 0x7FFFu + ((u >> 16) & 1u);
    return (unsigned short)(r >> 16);
}

// agent-scope ops: coherence-point access, no cache invalidation (r5-proven)
__device__ __forceinline__ float ato_ldf(const float* p) {
    return __hip_atomic_load((const float*)p, __ATOMIC_RELAXED, __HIP_MEMORY_SCOPE_AGENT);
}
__device__ __forceinline__ void ato_stf(float* p, float v) {
    __hip_atomic_store(p, v, __ATOMIC_RELAXED, __HIP_MEMORY_SCOPE_AGENT);
}

// ---------------------------------------------------------------------------
// RMW-FREE flag barrier: block i STORES its monotonic stamp to flag[i]
// (no exclusive-ownership transfer, no arrival serialization); lanes 0..nb-1
// of EVERY block poll all nb flags in parallel (one cacheline). No leader,
// no gen hop. Monotonic stamps -> no reset races.
// ---------------------------------------------------------------------------
__device__ __forceinline__ void flag_bar(unsigned* gbase, int idx, int nb, unsigned stamp)
{
    asm volatile("s_waitcnt vmcnt(0)" ::: "memory");
    __syncthreads();
    if (threadIdx.x == 0)
        __hip_atomic_store(gbase + idx, stamp, __ATOMIC_RELAXED, __HIP_MEMORY_SCOPE_AGENT);
    if ((int)threadIdx.x < nb) {
        while (__hip_atomic_load(gbase + threadIdx.x, __ATOMIC_RELAXED, __HIP_MEMORY_SCOPE_AGENT) < stamp)
            __builtin_amdgcn_s_sleep(1);
    }
    __syncthreads();
}

// ---------------------------------------------------------------------------
// Hierarchical barrier (only for encoder's one full 128-block sync at tail)
// ---------------------------------------------------------------------------
__device__ __forceinline__ void fast_barN(unsigned* base, int idx, unsigned ngroups)
{
    asm volatile("s_waitcnt vmcnt(0)" ::: "memory");
    __syncthreads();
    if (threadIdx.x == 0) {
        unsigned* gcnt = base + (idx >> 4) * 64;
        unsigned* ggen = gcnt + 32;
        unsigned* tcnt = base + ngroups * 64;
        unsigned* tgen = tcnt + 32;
        unsigned g0 = __hip_atomic_load(ggen, __ATOMIC_RELAXED, __HIP_MEMORY_SCOPE_AGENT);
        unsigned a  = __hip_atomic_fetch_add(gcnt, 1u, __ATOMIC_RELAXED, __HIP_MEMORY_SCOPE_AGENT);
        if (a == 15u) {
            unsigned t0 = __hip_atomic_load(tgen, __ATOMIC_RELAXED, __HIP_MEMORY_SCOPE_AGENT);
            unsigned ta = __hip_atomic_fetch_add(tcnt, 1u, __ATOMIC_RELAXED, __HIP_MEMORY_SCOPE_AGENT);
            if (ta == ngroups - 1u) {
                __hip_atomic_store(tcnt, 0u, __ATOMIC_RELAXED, __HIP_MEMORY_SCOPE_AGENT);
                __hip_atomic_store(tgen, t0 + 1u, __ATOMIC_RELAXED, __HIP_MEMORY_SCOPE_AGENT);
            } else {
                while (__hip_atomic_load(tgen, __ATOMIC_RELAXED, __HIP_MEMORY_SCOPE_AGENT) == t0)
                    __builtin_amdgcn_s_sleep(1);
            }
            __hip_atomic_store(gcnt, 0u, __ATOMIC_RELAXED, __HIP_MEMORY_SCOPE_AGENT);
            __hip_atomic_store(ggen, g0 + 1u, __ATOMIC_RELAXED, __HIP_MEMORY_SCOPE_AGENT);
        } else {
            while (__hip_atomic_load(ggen, __ATOMIC_RELAXED, __HIP_MEMORY_SCOPE_AGENT) == g0)
                __builtin_amdgcn_s_sleep(1);
        }
    }
    __syncthreads();
}

// ---------------------------------------------------------------------------
__global__ __launch_bounds__(256)
void prep_kernel(const int* __restrict__ src, const int* __restrict__ tgt,
                 int* __restrict__ tokf, int* __restrict__ tokb, int* __restrict__ tokd,
                 float* __restrict__ enc_h0, unsigned* __restrict__ bars)
{
    int tid = blockIdx.x * 256 + threadIdx.x;
    if (tid < S_ * B_) {
        int s = tid >> 5, b = tid & 31;
        tokf[tid] = src[b * S_ + s];
        tokb[tid] = src[b * S_ + (S_ - 1 - s)];
    }
    if (tid < TD_ * B_) {
        int t = tid >> 5, b = tid & 31;
        tokd[tid] = tgt[b * T_ + t];
    }
    if (tid < 2 * B_ * H_) enc_h0[tid] = 0.f;   // encrot slot 0
    if (tid < 4096) bars[tid] = 0u;
}

// ---------------------------------------------------------------------------
__global__ __launch_bounds__(256)
void emb_cat_kernel(const int* __restrict__ tokd, const float* __restrict__ dec_emb,
                    float* __restrict__ cat)
{
    int row = blockIdx.x;          // row = t*32 + b
    int tid = threadIdx.x;         // 0..255 == E_
    cat[(size_t)row * CATK_ + H_ + tid] = dec_emb[(size_t)tokd[row] * E_ + tid];
}

// ---------------------------------------------------------------------------
// Generic fp32 GEMM (small GEMMs + fallback fc1)
// ---------------------------------------------------------------------------
template<int GATHER, int FC1MAP>
__global__ __launch_bounds__(256)
void gemm128_kernel(const float* __restrict__ A, int lda,
                    const int* __restrict__ tokens, const float* __restrict__ emb,
                    const float* __restrict__ W, int ldw,
                    const float* __restrict__ bias,
                    float* __restrict__ C, int ldc,
                    int M, int N, int K)
{
    __shared__ float As[16][132];
    __shared__ float Ws[16][132];
    (void)N;
    int tid = threadIdx.x;
    int m0 = blockIdx.y * 128, n0 = blockIdx.x * 128;
    int tx = tid & 15, ty = tid >> 4;
    float c[8][8];
#pragma unroll
    for (int i = 0; i < 8; i++)
#pragma unroll
        for (int j = 0; j < 8; j++) c[i][j] = 0.f;

    int arow = tid >> 1;
    int kq = (tid & 1) * 8;

    int am = m0 + arow; if (am >= M) am = M - 1;
    const float* arp;
    if (GATHER) arp = emb + (size_t)tokens[am] * (size_t)K;
    else        arp = A + (size_t)am * (size_t)lda;
    const float* wrp = W + (size_t)(n0 + arow) * (size_t)ldw;

    for (int kb = 0; kb < K; kb += 16) {
        __syncthreads();
        float4 a0 = *(const float4*)(arp + kb + kq);
        float4 a1 = *(const float4*)(arp + kb + kq + 4);
        float4 w0 = *(const float4*)(wrp + kb + kq);
        float4 w1 = *(const float4*)(wrp + kb + kq + 4);
        As[kq + 0][arow] = a0.x; As[kq + 1][arow] = a0.y;
        As[kq + 2][arow] = a0.z; As[kq + 3][arow] = a0.w;
        As[kq + 4][arow] = a1.x; As[kq + 5][arow] = a1.y;
        As[kq + 6][arow] = a1.z; As[kq + 7][arow] = a1.w;
        Ws[kq + 0][arow] = w0.x; Ws[kq + 1][arow] = w0.y;
        Ws[kq + 2][arow] = w0.z; Ws[kq + 3][arow] = w0.w;
        Ws[kq + 4][arow] = w1.x; Ws[kq + 5][arow] = w1.y;
        Ws[kq + 6][arow] = w1.z; Ws[kq + 7][arow] = w1.w;
        __syncthreads();
#pragma unroll
        for (int kk = 0; kk < 16; kk++) {
            float a[8], bb[8];
            *(float4*)&a[0]  = *(const float4*)&As[kk][ty * 8];
            *(float4*)&a[4]  = *(const float4*)&As[kk][ty * 8 + 4];
            *(float4*)&bb[0] = *(const float4*)&Ws[kk][tx * 8];
            *(float4*)&bb[4] = *(const float4*)&Ws[kk][tx * 8 + 4];
#pragma unroll
            for (int i = 0; i < 8; i++)
#pragma unroll
                for (int j = 0; j < 8; j++) c[i][j] += a[i] * bb[j];
        }
    }

#pragma unroll
    for (int i = 0; i < 8; i++) {
        int m = m0 + ty * 8 + i;
        if (m < M) {
            size_t rowoff;
            if (FC1MAP) { int tt = m >> 5, bb2 = m & 31; rowoff = ((size_t)bb2 * T_ + tt) * (size_t)ldc; }
            else        rowoff = (size_t)m * (size_t)ldc;
#pragma unroll
            for (int j = 0; j < 8; j += 4) {
                int n = n0 + tx * 8 + j;
                float4 v;
                v.x = c[i][j + 0] + bias[n + 0];
                v.y = c[i][j + 1] + bias[n + 1];
                v.z = c[i][j + 2] + bias[n + 2];
                v.w = c[i][j + 3] + bias[n + 3];
                *(float4*)(C + rowoff + n) = v;
            }
        }
    }
}

// ---------------------------------------------------------------------------
// PERSISTENT bi-GRU encoder (r8-exact work layout, L2-resident weights):
// rotating h (cached reads, agent stores). Per-step barrier = 32-block
// producer group, RMW-free flag barrier.
// Tail (after one full barrier): enc_fc -> hT0 [b][k].
// ---------------------------------------------------------------------------
__global__ __launch_bounds__(256)
void enc_coop_kernel(const float* __restrict__ gxf, const float* __restrict__ gxb,
                     const float* __restrict__ Whh_f, const float* __restrict__ bhh_f,
                     const float* __restrict__ Whh_b, const float* __restrict__ bhh_b,
                     float* __restrict__ encrot, float* __restrict__ enc_bt,
                     const float* __restrict__ fcW, const float* __restrict__ fcb,
                     float* __restrict__ hT0, unsigned* __restrict__ bars)
{
    const int bid = blockIdx.x;
    const int dir = bid >> 6, bh = (bid >> 5) & 1, kc = bid & 31;
    const int tid = threadIdx.x;
    const int bl = tid & 15, kl = tid >> 4;
    const int b = bh * 16 + bl, k = kc * 16 + kl;
    const float* Whh = dir ? Whh_b : Whh_f;
    const float* bhhp = dir ? bhh_b : bhh_f;
    const float* gx  = dir ? gxb : gxf;
    __shared__ float hL[16 * 516];
    const float* wr = Whh + (size_t)k * H_;
    const float* wz = Whh + (size_t)(H_ + k) * H_;
    const float* wn = Whh + (size_t)(2 * H_ + k) * H_;
    const float b_r = bhhp[k], b_z = bhhp[H_ + k], b_n = bhhp[2 * H_ + k];
    unsigned* gbar = bars + (dir * 2 + bh) * 64;   // 32-flag group line
    unsigned stamp = 0;

    for (int t = 0; t < S_; ++t) {
        const float* hin = encrot + (size_t)t * (2 * B_ * H_) + (size_t)dir * (B_ * H_);
        float* hout = encrot + (size_t)(t + 1) * (2 * B_ * H_) + (size_t)dir * (B_ * H_);
        const float* hsrc = hin + (size_t)bh * 16 * H_;
        for (int i = tid * 4; i < 16 * H_; i += 1024) {
            int r = i >> 9, cix = i & 511;
            *(float4*)&hL[r * 516 + cix] = *(const float4*)(hsrc + i);
        }
        __syncthreads();
        float ar = 0.f, az = 0.f, an = 0.f;
        const float* hv = &hL[bl * 516];
#pragma unroll 4
        for (int j = 0; j < H_; j += 4) {
            float4 h4 = *(const float4*)(hv + j);
            float4 r4 = *(const float4*)(wr + j);
            float4 z4 = *(const float4*)(wz + j);
            float4 n4 = *(const float4*)(wn + j);
            ar += h4.x * r4.x + h4.y * r4.y + h4.z * r4.z + h4.w * r4.w;
            az += h4.x * z4.x + h4.y * z4.y + h4.z * z4.z + h4.w * z4.w;
            an += h4.x * n4.x + h4.y * n4.y + h4.z * n4.z + h4.w * n4.w;
        }
        const float* gxr = gx + ((size_t)t * B_ + b) * G3_;
        float xr = gxr[k], xz = gxr[H_ + k], xn = gxr[2 * H_ + k];
        float rg = 1.f / (1.f + expf(-(xr + ar + b_r)));
        float zg = 1.f / (1.f + expf(-(xz + az + b_z)));
        float ng = tanhf(xn + rg * (an + b_n));
        float hp = hL[bl * 516 + k];
        float h2 = (1.f - zg) * ng + zg * hp;
        ato_stf(hout + (size_t)b * H_ + k, h2);
        int s_out = dir ? (S_ - 1 - t) : t;
        enc_bt[((size_t)b * S_ + s_out) * (2 * H_) + dir * H_ + k] = h2;
        ++stamp;
        flag_bar(gbar, kc, 32, stamp);
    }
    fast_barN(bars + 1024, bid, 8);    // both dirs done (one-time)

    // tail: hidden = tanh([hf,hb] @ fcW.T + fcb) -> hT0[b][k]
    {
        const int b2 = bid & 31, ih = bid >> 5;
        float* hc = hL;
        const float* hfin = encrot + (size_t)S_ * (2 * B_ * H_);
        const float* hf  = hfin + (size_t)b2 * H_;
        const float* hbk = hfin + (size_t)B_ * H_ + (size_t)b2 * H_;
        for (int i = tid; i < H_; i += 256) { hc[i] = hf[i]; hc[H_ + i] = hbk[i]; }
        __syncthreads();
        if (tid < 128) {
            int i = ih * 128 + tid;
            const float* w = fcW + (size_t)i * (2 * H_);
            float acc = 0.f;
            for (int j = 0; j < 2 * H_; j += 4) {
                float4 a4 = *(const float4*)&hc[j];
                float4 w4 = *(const float4*)(w + j);
                acc += a4.x * w4.x + a4.y * w4.y + a4.z * w4.z + a4.w * w4.w;
            }
            ato_stf(hT0 + (size_t)b2 * H_ + i, tanhf(acc + fcb[i]));
        }
    }
}

// ---------------------------------------------------------------------------
// PERSISTENT attention decoder v14 (= v13 + flag barriers):
// 256 blocks = (b 32) x (sq 8); reg-resident projB/enc_bt slices;
// weights k-sliced, sq=bid%8 -> XCD L2-resident; 3 flag barriers/step.
// ---------------------------------------------------------------------------
__global__ __launch_bounds__(256)
void dec_coop_kernel(const float* __restrict__ attn_W, const float* __restrict__ attn_v,
                     const float* __restrict__ enc_projB, const float* __restrict__ enc_bt,
                     const int* __restrict__ src,
                     const float* __restrict__ dWhh, const float* __restrict__ dbhh,
                     const float* __restrict__ dWih, const float* __restrict__ gx_emb,
                     float* __restrict__ cat, float* __restrict__ hT,
                     float* __restrict__ hwhT, float* __restrict__ wpart,
                     float* __restrict__ mlq, unsigned* __restrict__ bars)
{
    const int bid = blockIdx.x, tid = threadIdx.x;
    const int b = bid >> 3, sq = bid & 7;
    const int k0 = sq * 64, s0 = sq * 16;
    __shared__ float hA[512], hwhL[512], vL[512];
    __shared__ float ghhL[192], xwL[192], wL[1024];
    __shared__ float sLq[16], eSq[16], cmbL[16];
    unsigned* gbar = bars + 2048 + b * 64;
    unsigned stamp = 0;

    const int ps = tid >> 4, pu = tid & 15;
    // ---- constant register slices (loaded once) ----
    float projreg[32];
    {
        const float* pr = enc_projB + ((size_t)b * S_ + s0 + ps) * H_ + pu * 32;
#pragma unroll
        for (int i = 0; i < 32; i += 4) {
            float4 v = *(const float4*)(pr + i);
            projreg[i] = v.x; projreg[i + 1] = v.y; projreg[i + 2] = v.z; projreg[i + 3] = v.w;
        }
    }
    float ebtreg[16][4];
    {
        const int c4 = tid * 4;
#pragma unroll
        for (int s = 0; s < 16; s++) {
            float4 v = *(const float4*)(enc_bt + ((size_t)b * S_ + s0 + s) * (2 * H_) + c4);
            ebtreg[s][0] = v.x; ebtreg[s][1] = v.y; ebtreg[s][2] = v.z; ebtreg[s][3] = v.w;
        }
    }
    for (int i = tid; i < H_; i += 256) vL[i] = attn_v[i];
    const int msk = (src[b * S_ + s0 + ps] != 0);

    // P0 row task (constant across steps)
    const float* w0row;
    float bias0 = 0.f;
    if (tid < 64) w0row = attn_W + (size_t)(k0 + tid) * G3_;
    else {
        int rr = tid - 64;
        int grow = (rr >> 6) * H_ + k0 + (rr & 63);
        w0row = dWhh + (size_t)grow * H_;
        bias0 = dbhh[grow];
    }

    for (int t = 0; t < TD_; ++t) {
        const int pp = t & 1;
        const float* hin = hT + (size_t)pp * (B_ * H_);
        float* hout = hT + (size_t)(1 - pp) * (B_ * H_);
        float* cat_t = cat + (size_t)t * B_ * CATK_;

        // ---- P0: h[b] -> hwh (64 rows, global) + ghh (192 rows, LDS) ----
        for (int j = tid; j < H_; j += 256) hA[j] = ato_ldf(hin + (size_t)b * H_ + j);
        __syncthreads();
        {
            float a0 = 0.f, a1 = 0.f;
            for (int j = 0; j < H_; j += 8) {
                float4 w0 = *(const float4*)(w0row + j);
                float4 w1 = *(const float4*)(w0row + j + 4);
                float4 h0 = *(const float4*)&hA[j];
                float4 h1 = *(const float4*)&hA[j + 4];
                a0 += w0.x * h0.x + w0.y * h0.y + w0.z * h0.z + w0.w * h0.w;
                a1 += w1.x * h1.x + w1.y * h1.y + w1.z * h1.z + w1.w * h1.w;
            }
            float acc = a0 + a1;
            if (tid < 64) ato_stf(hwhT + (size_t)b * H_ + k0 + tid, acc);
            else ghhL[tid - 64] = acc + bias0;
        }
        ++stamp;
        flag_bar(gbar, sq, 8, stamp);

        // ---- P1: scores (reg-resident proj) + local softmax + partial w ----
        for (int i = tid; i < H_; i += 256) hwhL[i] = ato_ldf(hwhT + (size_t)b * H_ + i);
        __syncthreads();
        {
            float acc = 0.f;
#pragma unroll
            for (int i = 0; i < 32; i++) {
                int e = pu * 32 + i;
                float x = hwhL[e] + projreg[i];
                float e2 = __expf(2.f * x);
                acc += vL[e] * (1.f - 2.f / (e2 + 1.f));
            }
            acc += __shfl_xor(acc, 1);
            acc += __shfl_xor(acc, 2);
            acc += __shfl_xor(acc, 4);
            acc += __shfl_xor(acc, 8);
            if (pu == 0) sLq[ps] = msk ? acc : -1e10f;
        }
        __syncthreads();
        if (tid < 16) {
            float v = sLq[tid];
            float m = v;
#pragma unroll
            for (int off = 1; off < 16; off <<= 1) m = fmaxf(m, __shfl_xor(m, off));
            float e = expf(v - m);
            eSq[tid] = e;
            float l = e;
#pragma unroll
            for (int off = 1; off < 16; off <<= 1) l += __shfl_xor(l, off);
            if (tid == 0) {
                ato_stf(mlq + (size_t)(b * 8 + sq) * 2 + 0, m);
                ato_stf(mlq + (size_t)(b * 8 + sq) * 2 + 1, l);
            }
        }
        __syncthreads();
        {
            float x0 = 0.f, x1 = 0.f, x2 = 0.f, x3 = 0.f;
#pragma unroll
            for (int s = 0; s < 16; s++) {
                float es = eSq[s];
                x0 += es * ebtreg[s][0]; x1 += es * ebtreg[s][1];
                x2 += es * ebtreg[s][2]; x3 += es * ebtreg[s][3];
            }
            float* dst = wpart + (size_t)(b * 8 + sq) * 1024 + tid * 4;
            ato_stf(dst + 0, x0); ato_stf(dst + 1, x1);
            ato_stf(dst + 2, x2); ato_stf(dst + 3, x3);
        }
        ++stamp;
        flag_bar(gbar, sq, 8, stamp);

        // ---- P2: combine -> w (LDS) -> xw -> gates -> h' + cat ----
        if (tid < 16) cmbL[tid] = ato_ldf(mlq + (size_t)(b * 8 + (tid >> 1)) * 2 + (tid & 1));
        __syncthreads();
        {
            float m = cmbL[0];
#pragma unroll
            for (int q = 1; q < 8; q++) m = fmaxf(m, cmbL[2 * q]);
            float eq[8]; float L = 0.f;
#pragma unroll
            for (int q = 0; q < 8; q++) { eq[q] = expf(cmbL[2 * q] - m); L += eq[q] * cmbL[2 * q + 1]; }
            float inv = 1.f / L;
            int c4 = tid * 4;
            float w0 = 0.f, w1 = 0.f, w2 = 0.f, w3 = 0.f;
#pragma unroll
            for (int q = 0; q < 8; q++) {
                const float* p = wpart + (size_t)(b * 8 + q) * 1024 + c4;
                float e = eq[q];
                w0 += e * ato_ldf(p + 0); w1 += e * ato_ldf(p + 1);
                w2 += e * ato_ldf(p + 2); w3 += e * ato_ldf(p + 3);
            }
            w0 *= inv; w1 *= inv; w2 *= inv; w3 *= inv;
            wL[c4 + 0] = w0; wL[c4 + 1] = w1; wL[c4 + 2] = w2; wL[c4 + 3] = w3;
            if (sq == 0) {
                float4 o; o.x = w0; o.y = w1; o.z = w2; o.w = w3;
                *(float4*)(cat_t + (size_t)b * CATK_ + (H_ + E_) + c4) = o;
            }
        }
        __syncthreads();
        if (tid < 192) {
            int grow = (tid >> 6) * H_ + k0 + (tid & 63);
            const float* wrow = dWih + (size_t)grow * DIN_ + E_;
            float a0 = 0.f, a1 = 0.f;
            for (int c = 0; c < 2 * H_; c += 8) {
                float4 w0 = *(const float4*)(wrow + c);
                float4 w1 = *(const float4*)(wrow + c + 4);
                float4 x0 = *(const float4*)&wL[c];
                float4 x1 = *(const float4*)&wL[c + 4];
                a0 += w0.x * x0.x + w0.y * x0.y + w0.z * x0.z + w0.w * x0.w;
                a1 += w1.x * x1.x + w1.y * x1.y + w1.z * x1.z + w1.w * x1.w;
            }
            xwL[tid] = a0 + a1;
        }
        __syncthreads();
        if (tid < 64) {
            int k = k0 + tid;
            float hr = ghhL[tid], hz = ghhL[64 + tid], hn = ghhL[128 + tid];
            float xr = xwL[tid], xz = xwL[64 + tid], xn = xwL[128 + tid];
            const float* gxe = gx_emb + ((size_t)t * B_ + b) * G3_;
            float rg = 1.f / (1.f + expf(-(gxe[k] + xr + hr)));
            float zg = 1.f / (1.f + expf(-(gxe[H_ + k] + xz + hz)));
            float ng = tanhf(gxe[2 * H_ + k] + xn + rg * hn);
            float hp = hA[k];
            float h2 = (1.f - zg) * ng + zg * hp;
            ato_stf(hout + (size_t)b * H_ + k, h2);
            cat_t[(size_t)b * CATK_ + k] = h2;
        }
        ++stamp;
        flag_bar(gbar, sq, 8, stamp);
    }
}

// ---------------------------------------------------------------------------
__global__ __launch_bounds__(256)
void splitA_kernel(const float* __restrict__ cat,
                   unsigned short* __restrict__ Ahi, unsigned short* __restrict__ Alo)
{
    size_t i4 = ((size_t)blockIdx.x * 256 + threadIdx.x) * 4;
    if (i4 >= (size_t)MPAD_ * CATK_) return;
    size_t row = i4 / CATK_;
    float4 v;
    if (row < (size_t)TD_ * B_) v = *(const float4*)(cat + i4);
    else { v.x = v.y = v.z = v.w = 0.f; }
    float f[4] = {v.x, v.y, v.z, v.w};
    unsigned short h[4], l[4];
#pragma unroll
    for (int j = 0; j < 4; j++) {
        h[j] = bf16_rne(f[j]);
        float hf = __uint_as_float((unsigned)h[j] << 16);
        l[j] = bf16_rne(f[j] - hf);
    }
    *(ushort4*)(Ahi + i4) = make_ushort4(h[0], h[1], h[2], h[3]);
    *(ushort4*)(Alo + i4) = make_ushort4(l[0], l[1], l[2], l[3]);
}

// ---------------------------------------------------------------------------
__global__ __launch_bounds__(256)
void fc1_mfma_kernel(const unsigned short* __restrict__ Ahi,
                     const unsigned short* __restrict__ Alo,
                     const float* __restrict__ W,
                     const float* __restrict__ bias,
                     float* __restrict__ C)
{
    __shared__ unsigned short lA[2][128][40];
    __shared__ unsigned short lW[2][128][40];
    const int tid = threadIdx.x;
    const int m0 = blockIdx.x * 128, n0 = blockIdx.y * 128;
    const int w = tid >> 6, lane = tid & 63;
    const int wm = w >> 1, wn = w & 1;
    const int frow = lane & 15, fk = (lane >> 4) * 8;

    f32x4 acc[4][4];
#pragma unroll
    for (int mi = 0; mi < 4; mi++)
#pragma unroll
        for (int ni = 0; ni < 4; ni++) acc[mi][ni] = (f32x4){0.f, 0.f, 0.f, 0.f};

    const int srow = tid >> 1;
    const int skq = (tid & 1) * 16;

    const unsigned short* gAhi = Ahi + (size_t)(m0 + srow) * CATK_ + skq;
    const unsigned short* gAlo = Alo + (size_t)(m0 + srow) * CATK_ + skq;
    const float*          gW   = W   + (size_t)(n0 + srow) * CATK_ + skq;

    int4 rAh0, rAh1, rAl0, rAl1;
    float4 rW0, rW1, rW2, rW3;

#define FC1_LOAD(kb)                                        \
    do {                                                    \
        rAh0 = *(const int4*)(gAhi + (kb));                 \
        rAh1 = *(const int4*)(gAhi + (kb) + 8);             \
        rAl0 = *(const int4*)(gAlo + (kb));                 \
        rAl1 = *(const int4*)(gAlo + (kb) + 8);             \
        rW0  = *(const float4*)(gW + (kb));                 \
        rW1  = *(const float4*)(gW + (kb) + 4);             \
        rW2  = *(const float4*)(gW + (kb) + 8);             \
        rW3  = *(const float4*)(gW + (kb) + 12);            \
    } while (0)

    FC1_LOAD(0);

    for (int kb = 0; kb < CATK_; kb += 32) {
        __syncthreads();
        *(int4*)&lA[0][srow][skq]     = rAh0;
        *(int4*)&lA[0][srow][skq + 8] = rAh1;
        *(int4*)&lA[1][srow][skq]     = rAl0;
        *(int4*)&lA[1][srow][skq + 8] = rAl1;
        {
            float f[16] = {rW0.x, rW0.y, rW0.z, rW0.w, rW1.x, rW1.y, rW1.z, rW1.w,
                           rW2.x, rW2.y, rW2.z, rW2.w, rW3.x, rW3.y, rW3.z, rW3.w};
            unsigned hp[8], lp[8];
#pragma unroll
            for (int j = 0; j < 8; j++) {
                float x0 = f[2 * j], x1 = f[2 * j + 1];
                unsigned short h0 = bf16_rne(x0), h1 = bf16_rne(x1);
                float r0 = x0 - __uint_as_float((unsigned)h0 << 16);
                float r1 = x1 - __uint_as_float((unsigned)h1 << 16);
                hp[j] = (unsigned)h0 | ((unsigned)h1 << 16);
                lp[j] = (unsigned)bf16_rne(r0) | ((unsigned)bf16_rne(r1) << 16);
            }
            *(int4*)&lW[0][srow][skq]     = make_int4(hp[0], hp[1], hp[2], hp[3]);
            *(int4*)&lW[0][srow][skq + 8] = make_int4(hp[4], hp[5], hp[6], hp[7]);
            *(int4*)&lW[1][srow][skq]     = make_int4(lp[0], lp[1], lp[2], lp[3]);
            *(int4*)&lW[1][srow][skq + 8] = make_int4(lp[4], lp[5], lp[6], lp[7]);
        }
        __syncthreads();
        if (kb + 32 < CATK_) FC1_LOAD(kb + 32);

        bf16x8 a[2][4];
#pragma unroll
        for (int mi = 0; mi < 4; mi++) {
            int r = wm * 64 + mi * 16 + frow;
            a[0][mi] = *(const bf16x8*)&lA[0][r][fk];
            a[1][mi] = *(const bf16x8*)&lA[1][r][fk];
        }
#pragma unroll
        for (int ni = 0; ni < 4; ni++) {
            int r = wn * 64 + ni * 16 + frow;
            bf16x8 bh = *(const bf16x8*)&lW[0][r][fk];
            bf16x8 bl = *(const bf16x8*)&lW[1][r][fk];
#pragma unroll
            for (int mi = 0; mi < 4; mi++) {
                acc[mi][ni] = __builtin_amdgcn_mfma_f32_16x16x32_bf16(a[0][mi], bh, acc[mi][ni], 0, 0, 0);
                acc[mi][ni] = __builtin_amdgcn_mfma_f32_16x16x32_bf16(a[1][mi], bh, acc[mi][ni], 0, 0, 0);
                acc[mi][ni] = __builtin_amdgcn_mfma_f32_16x16x32_bf16(a[0][mi], bl, acc[mi][ni], 0, 0, 0);
            }
        }
    }
#undef FC1_LOAD

#pragma unroll
    for (int ni = 0; ni < 4; ni++) {
        int col = n0 + wn * 64 + ni * 16 + frow;
        float bc = bias[col];
#pragma unroll
        for (int mi = 0; mi < 4; mi++) {
            int mbase = m0 + wm * 64 + mi * 16 + (lane >> 4) * 4;
            f32x4 v = acc[mi][ni];
#pragma unroll
            for (int r = 0; r < 4; r++) {
                int m = mbase + r;
                if (m < TD_ * B_) {
                    int tt = m >> 5, bb2 = m & 31;
                    C[((size_t)bb2 * T_ + tt) * V_ + col] = v[r] + bc;
                }
            }
        }
    }
}

// ---------------------------------------------------------------------------
__global__ __launch_bounds__(256)
void argmax_kernel(const float* __restrict__ outp, float* __restrict__ preds)
{
    int row = blockIdx.x;
    int t = row >> 5, b = row & 31;
    const float* p = outp + ((size_t)b * T_ + t) * V_;
    int tid = threadIdx.x;
    float best = -3.4e38f; int bi = V_;
    for (int i = tid; i < V_; i += 256) {
        float v = p[i];
        if (v > best) { best = v; bi = i; }
    }
    __shared__ float bv[256];
    __shared__ int bidx[256];
    bv[tid] = best; bidx[tid] = bi;
    __syncthreads();
    for (int off = 128; off > 0; off >>= 1) {
        if (tid < off) {
            float v2 = bv[tid + off]; int i2 = bidx[tid + off];
            if (v2 > bv[tid] || (v2 == bv[tid] && i2 < bidx[tid])) { bv[tid] = v2; bidx[tid] = i2; }
        }
        __syncthreads();
    }
    if (tid == 0) preds[(size_t)b * T_ + t] = (float)bidx[0];
}

// ---------------------------------------------------------------------------
__global__ __launch_bounds__(256)
void zero_tail_kernel(float* __restrict__ outp, float* __restrict__ preds)
{
    int tid = blockIdx.x * 256 + threadIdx.x;
    if (tid < B_ * V_) {
        int b = tid / V_;
        int c = tid % V_;
        outp[((size_t)b * T_ + (T_ - 1)) * V_ + c] = 0.f;
    }
    if (tid < B_) preds[(size_t)tid * T_ + (T_ - 1)] = 0.f;
}

// ---------------------------------------------------------------------------
extern "C" void kernel_launch(void* const* d_in, const int* in_sizes, int n_in,
                              void* d_out, int out_size, void* d_ws, size_t ws_size,
                              hipStream_t stream)
{
    (void)in_sizes; (void)n_in; (void)out_size;
    const int*   src     = (const int*)d_in[0];
    const int*   tgt     = (const int*)d_in[1];
    const float* enc_emb = (const float*)d_in[2];
    const float* Wih_f   = (const float*)d_in[3];
    const float* Whh_f   = (const float*)d_in[4];
    const float* bih_f   = (const float*)d_in[5];
    const float* bhh_f   = (const float*)d_in[6];
    const float* Wih_b   = (const float*)d_in[7];
    const float* Whh_b   = (const float*)d_in[8];
    const float* bih_b   = (const float*)d_in[9];
    const float* bhh_b   = (const float*)d_in[10];
    const float* fcW     = (const float*)d_in[11];
    const float* fcb     = (const float*)d_in[12];
    const float* dec_emb = (const float*)d_in[13];
    const float* attn_W  = (const float*)d_in[14];
    const float* attn_b  = (const float*)d_in[15];
    const float* attn_v  = (const float*)d_in[16];
    const float* dWih    = (const float*)d_in[17];
    const float* dWhh    = (const float*)d_in[18];
    const float* dbih    = (const float*)d_in[19];
    const float* dbhh    = (const float*)d_in[20];
    const float* fc1W    = (const float*)d_in[21];
    const float* fc1b    = (const float*)d_in[22];
    (void)dbih;

    // ws layout
    float* ws     = (float*)d_ws;
    float* cat    = ws;                                  // 3,612,672 f
    float* gx_emb = cat + (size_t)TD_ * B_ * CATK_;      // 3,096,576 f
    int*   tokf   = (int*)(gx_emb + (size_t)TD_ * B_ * G3_);
    int*   tokb   = tokf + 4096;
    int*   tokd   = tokb + 4096;
    unsigned* bars = (unsigned*)(tokd + 4096);           // 4096 u: enc flags 0..255,
                                                         // enc full @1024, dec flags @2048
    unsigned short* Ahi = (unsigned short*)(bars + 4096);
    unsigned short* Alo = Ahi + (size_t)MPAD_ * CATK_;
    size_t ws_req = (size_t)((char*)(Alo + (size_t)MPAD_ * CATK_) - (char*)d_ws);
    const bool use_mfma = (ws_size >= ws_req);

    // d_out scratch (fully overwritten by fc1 + zero_tail afterwards)
    float* dout      = (float*)d_out;
    float* gxf       = dout;                                        // 6,291,456
    float* gxb       = gxf + (size_t)S_ * B_ * G3_;                 // 6,291,456
    float* enc_bt    = gxb + (size_t)S_ * B_ * G3_;                 // 4,194,304
    float* enc_projB = enc_bt + (size_t)B_ * S_ * 2 * H_;           // 2,097,152
    float* encrot    = enc_projB + (size_t)B_ * S_ * H_;            // 129 x 32,768
    float* hT        = encrot + (size_t)(S_ + 1) * 2 * B_ * H_;     // 2 x 16,384 ([pp][b][k])
    float* hwhT      = hT + 2 * B_ * H_;                            // 16,384 ([b][k])
    float* wpart     = hwhT + B_ * H_;                              // 262,144 ([b][q8][1024])
    float* mlq       = wpart + (size_t)B_ * 8 * 1024;               // 512
    float* preds     = dout + (size_t)B_ * T_ * V_;

    dim3 thr(256);

    hipLaunchKernelGGL(prep_kernel, dim3(256), thr, 0, stream,
                       src, tgt, tokf, tokb, tokd, encrot, bars);
    hipLaunchKernelGGL(emb_cat_kernel, dim3(TD_ * B_), thr, 0, stream, tokd, dec_emb, cat);

    hipLaunchKernelGGL((gemm128_kernel<1, 0>), dim3(G3_ / 128, (S_ * B_) / 128), thr, 0, stream,
                       (const float*)nullptr, 0, tokf, enc_emb, Wih_f, E_, bih_f,
                       gxf, G3_, S_ * B_, G3_, E_);
    hipLaunchKernelGGL((gemm128_kernel<1, 0>), dim3(G3_ / 128, (S_ * B_) / 128), thr, 0, stream,
                       (const float*)nullptr, 0, tokb, enc_emb, Wih_b, E_, bih_b,
                       gxb, G3_, S_ * B_, G3_, E_);

    // encoder recurrence + enc_fc in ONE launch (128 blocks, flag barriers)
    hipLaunchKernelGGL(enc_coop_kernel, dim3(128), thr, 0, stream,
                       gxf, gxb, Whh_f, bhh_f, Whh_b, bhh_b, encrot, enc_bt,
                       fcW, fcb, hT /* slot 0, [b][k] */, bars);

    hipLaunchKernelGGL((gemm128_kernel<0, 0>), dim3(H_ / 128, (B_ * S_) / 128), thr, 0, stream,
                       enc_bt, 2 * H_, (const int*)nullptr, (const float*)nullptr,
                       attn_W + H_, G3_, attn_b, enc_projB, H_, B_ * S_, H_, 2 * H_);

    hipLaunchKernelGGL((gemm128_kernel<1, 0>), dim3(G3_ / 128, (TD_ * B_ + 127) / 128), thr, 0, stream,
                       (const float*)nullptr, 0, tokd, dec_emb, dWih, DIN_, dbih,
                       gx_emb, G3_, TD_ * B_, G3_, E_);

    // decoder recurrence in ONE launch (256 blocks, flag barriers)
    hipLaunchKernelGGL(dec_coop_kernel, dim3(256), thr, 0, stream,
                       attn_W, attn_v, enc_projB, enc_bt, src,
                       dWhh, dbhh, dWih, gx_emb, cat, hT, hwhT, wpart, mlq,
                       bars);

    if (use_mfma) {
        hipLaunchKernelGGL(splitA_kernel, dim3((MPAD_ * CATK_ / 4 + 255) / 256), thr, 0, stream,
                           cat, Ahi, Alo);
        hipLaunchKernelGGL(fc1_mfma_kernel, dim3(MPAD_ / 128, V_ / 128), thr, 0, stream,
                           Ahi, Alo, fc1W, fc1b, dout);
    } else {
        hipLaunchKernelGGL((gemm128_kernel<0, 1>), dim3(V_ / 128, (TD_ * B_ + 127) / 128), thr, 0, stream,
                           cat, CATK_, (const int*)nullptr, (const float*)nullptr,
                           fc1W, CATK_, fc1b, dout, V_, TD_ * B_, V_, CATK_);
    }

    hipLaunchKernelGGL(argmax_kernel, dim3(TD_ * B_), thr, 0, stream, dout, preds);
    hipLaunchKernelGGL(zero_tail_kernel, dim3((B_ * V_ + 255) / 256), thr, 0, stream, dout, preds);
}

// Round 15
// 4928.413 us; speedup vs baseline: 1.5086x; 1.2260x over previous
//
#include <hip/hip_runtime.h>

#define V_ 32000
#define E_ 256
#define H_ 512
#define B_ 32
#define S_ 128
#define T_ 64
#define TD_ 63        // decoder steps (T-1)
#define G3_ 1536      // 3*H
#define CATK_ 1792    // H + E + 2H
#define DIN_ 1280     // E + 2H
#define MPAD_ 2048    // padded M for fc1 MFMA
#define MBS_ 4096     // B_*S_

typedef __attribute__((ext_vector_type(8))) short bf16x8;
typedef __attribute__((ext_vector_type(4))) float f32x4;

__device__ inline unsigned short bf16_rne(float x) {
    unsigned u = __float_as_uint(x);
    unsigned r = u + 0x7FFFu + ((u >> 16) & 1u);
    return (unsigned short)(r >> 16);
}

// agent-scope ops: coherence-point access, no cache invalidation (r5-proven)
__device__ __forceinline__ float ato_ldf(const float* p) {
    return __hip_atomic_load((const float*)p, __ATOMIC_RELAXED, __HIP_MEMORY_SCOPE_AGENT);
}
__device__ __forceinline__ void ato_stf(float* p, float v) {
    __hip_atomic_store(p, v, __ATOMIC_RELAXED, __HIP_MEMORY_SCOPE_AGENT);
}

// ---------------------------------------------------------------------------
// RMW-free flag barrier (r14-proven): block i stores monotonic stamp; lanes
// 0..nb-1 poll all flags in parallel. Fence-free (agent-atomic data path).
// ---------------------------------------------------------------------------
__device__ __forceinline__ void flag_bar(unsigned* gbase, int idx, int nb, unsigned stamp)
{
    asm volatile("s_waitcnt vmcnt(0)" ::: "memory");
    __syncthreads();
    if (threadIdx.x == 0)
        __hip_atomic_store(gbase + idx, stamp, __ATOMIC_RELAXED, __HIP_MEMORY_SCOPE_AGENT);
    if ((int)threadIdx.x < nb) {
        while (__hip_atomic_load(gbase + threadIdx.x, __ATOMIC_RELAXED, __HIP_MEMORY_SCOPE_AGENT) < stamp)
            __builtin_amdgcn_s_sleep(1);
    }
    __syncthreads();
}

// ---------------------------------------------------------------------------
// Hierarchical barrier (encoder's one full 128-block sync at tail)
// ---------------------------------------------------------------------------
__device__ __forceinline__ void fast_barN(unsigned* base, int idx, unsigned ngroups)
{
    asm volatile("s_waitcnt vmcnt(0)" ::: "memory");
    __syncthreads();
    if (threadIdx.x == 0) {
        unsigned* gcnt = base + (idx >> 4) * 64;
        unsigned* ggen = gcnt + 32;
        unsigned* tcnt = base + ngroups * 64;
        unsigned* tgen = tcnt + 32;
        unsigned g0 = __hip_atomic_load(ggen, __ATOMIC_RELAXED, __HIP_MEMORY_SCOPE_AGENT);
        unsigned a  = __hip_atomic_fetch_add(gcnt, 1u, __ATOMIC_RELAXED, __HIP_MEMORY_SCOPE_AGENT);
        if (a == 15u) {
            unsigned t0 = __hip_atomic_load(tgen, __ATOMIC_RELAXED, __HIP_MEMORY_SCOPE_AGENT);
            unsigned ta = __hip_atomic_fetch_add(tcnt, 1u, __ATOMIC_RELAXED, __HIP_MEMORY_SCOPE_AGENT);
            if (ta == ngroups - 1u) {
                __hip_atomic_store(tcnt, 0u, __ATOMIC_RELAXED, __HIP_MEMORY_SCOPE_AGENT);
                __hip_atomic_store(tgen, t0 + 1u, __ATOMIC_RELAXED, __HIP_MEMORY_SCOPE_AGENT);
            } else {
                while (__hip_atomic_load(tgen, __ATOMIC_RELAXED, __HIP_MEMORY_SCOPE_AGENT) == t0)
                    __builtin_amdgcn_s_sleep(1);
            }
            __hip_atomic_store(gcnt, 0u, __ATOMIC_RELAXED, __HIP_MEMORY_SCOPE_AGENT);
            __hip_atomic_store(ggen, g0 + 1u, __ATOMIC_RELAXED, __HIP_MEMORY_SCOPE_AGENT);
        } else {
            while (__hip_atomic_load(ggen, __ATOMIC_RELAXED, __HIP_MEMORY_SCOPE_AGENT) == g0)
                __builtin_amdgcn_s_sleep(1);
        }
    }
    __syncthreads();
}

// ---------------------------------------------------------------------------
__global__ __launch_bounds__(256)
void prep_kernel(const int* __restrict__ src, const int* __restrict__ tgt,
                 int* __restrict__ tokf, int* __restrict__ tokb, int* __restrict__ tokd,
                 float* __restrict__ enc_h0, unsigned* __restrict__ bars)
{
    int tid = blockIdx.x * 256 + threadIdx.x;
    if (tid < S_ * B_) {
        int s = tid >> 5, b = tid & 31;
        tokf[tid] = src[b * S_ + s];
        tokb[tid] = src[b * S_ + (S_ - 1 - s)];
    }
    if (tid < TD_ * B_) {
        int t = tid >> 5, b = tid & 31;
        tokd[tid] = tgt[b * T_ + t];
    }
    if (tid < 2 * B_ * H_) enc_h0[tid] = 0.f;   // encrot slot 0
    if (tid < 4096) bars[tid] = 0u;
}

// ---------------------------------------------------------------------------
__global__ __launch_bounds__(256)
void emb_cat_kernel(const int* __restrict__ tokd, const float* __restrict__ dec_emb,
                    float* __restrict__ cat)
{
    int row = blockIdx.x;          // row = t*32 + b
    int tid = threadIdx.x;         // 0..255 == E_
    cat[(size_t)row * CATK_ + H_ + tid] = dec_emb[(size_t)tokd[row] * E_ + tid];
}

// ---------------------------------------------------------------------------
// Generic fp32 GEMM (small GEMMs + fallback fc1)
// ---------------------------------------------------------------------------
template<int GATHER, int FC1MAP>
__global__ __launch_bounds__(256)
void gemm128_kernel(const float* __restrict__ A, int lda,
                    const int* __restrict__ tokens, const float* __restrict__ emb,
                    const float* __restrict__ W, int ldw,
                    const float* __restrict__ bias,
                    float* __restrict__ C, int ldc,
                    int M, int N, int K)
{
    __shared__ float As[16][132];
    __shared__ float Ws[16][132];
    (void)N;
    int tid = threadIdx.x;
    int m0 = blockIdx.y * 128, n0 = blockIdx.x * 128;
    int tx = tid & 15, ty = tid >> 4;
    float c[8][8];
#pragma unroll
    for (int i = 0; i < 8; i++)
#pragma unroll
        for (int j = 0; j < 8; j++) c[i][j] = 0.f;

    int arow = tid >> 1;
    int kq = (tid & 1) * 8;

    int am = m0 + arow; if (am >= M) am = M - 1;
    const float* arp;
    if (GATHER) arp = emb + (size_t)tokens[am] * (size_t)K;
    else        arp = A + (size_t)am * (size_t)lda;
    const float* wrp = W + (size_t)(n0 + arow) * (size_t)ldw;

    for (int kb = 0; kb < K; kb += 16) {
        __syncthreads();
        float4 a0 = *(const float4*)(arp + kb + kq);
        float4 a1 = *(const float4*)(arp + kb + kq + 4);
        float4 w0 = *(const float4*)(wrp + kb + kq);
        float4 w1 = *(const float4*)(wrp + kb + kq + 4);
        As[kq + 0][arow] = a0.x; As[kq + 1][arow] = a0.y;
        As[kq + 2][arow] = a0.z; As[kq + 3][arow] = a0.w;
        As[kq + 4][arow] = a1.x; As[kq + 5][arow] = a1.y;
        As[kq + 6][arow] = a1.z; As[kq + 7][arow] = a1.w;
        Ws[kq + 0][arow] = w0.x; Ws[kq + 1][arow] = w0.y;
        Ws[kq + 2][arow] = w0.z; Ws[kq + 3][arow] = w0.w;
        Ws[kq + 4][arow] = w1.x; Ws[kq + 5][arow] = w1.y;
        Ws[kq + 6][arow] = w1.z; Ws[kq + 7][arow] = w1.w;
        __syncthreads();
#pragma unroll
        for (int kk = 0; kk < 16; kk++) {
            float a[8], bb[8];
            *(float4*)&a[0]  = *(const float4*)&As[kk][ty * 8];
            *(float4*)&a[4]  = *(const float4*)&As[kk][ty * 8 + 4];
            *(float4*)&bb[0] = *(const float4*)&Ws[kk][tx * 8];
            *(float4*)&bb[4] = *(const float4*)&Ws[kk][tx * 8 + 4];
#pragma unroll
            for (int i = 0; i < 8; i++)
#pragma unroll
                for (int j = 0; j < 8; j++) c[i][j] += a[i] * bb[j];
        }
    }

#pragma unroll
    for (int i = 0; i < 8; i++) {
        int m = m0 + ty * 8 + i;
        if (m < M) {
            size_t rowoff;
            if (FC1MAP) { int tt = m >> 5, bb2 = m & 31; rowoff = ((size_t)bb2 * T_ + tt) * (size_t)ldc; }
            else        rowoff = (size_t)m * (size_t)ldc;
#pragma unroll
            for (int j = 0; j < 8; j += 4) {
                int n = n0 + tx * 8 + j;
                float4 v;
                v.x = c[i][j + 0] + bias[n + 0];
                v.y = c[i][j + 1] + bias[n + 1];
                v.z = c[i][j + 2] + bias[n + 2];
                v.w = c[i][j + 3] + bias[n + 3];
                *(float4*)(C + rowoff + n) = v;
            }
        }
    }
}

// ---------------------------------------------------------------------------
// PERSISTENT bi-GRU encoder (r14-exact): rotating h, cached reads, agent
// stores, 32-block flag barrier per step. Tail: enc_fc -> hT0 [b][k].
// ---------------------------------------------------------------------------
__global__ __launch_bounds__(256)
void enc_coop_kernel(const float* __restrict__ gxf, const float* __restrict__ gxb,
                     const float* __restrict__ Whh_f, const float* __restrict__ bhh_f,
                     const float* __restrict__ Whh_b, const float* __restrict__ bhh_b,
                     float* __restrict__ encrot, float* __restrict__ enc_bt,
                     const float* __restrict__ fcW, const float* __restrict__ fcb,
                     float* __restrict__ hT0, unsigned* __restrict__ bars)
{
    const int bid = blockIdx.x;
    const int dir = bid >> 6, bh = (bid >> 5) & 1, kc = bid & 31;
    const int tid = threadIdx.x;
    const int bl = tid & 15, kl = tid >> 4;
    const int b = bh * 16 + bl, k = kc * 16 + kl;
    const float* Whh = dir ? Whh_b : Whh_f;
    const float* bhhp = dir ? bhh_b : bhh_f;
    const float* gx  = dir ? gxb : gxf;
    __shared__ float hL[16 * 516];
    const float* wr = Whh + (size_t)k * H_;
    const float* wz = Whh + (size_t)(H_ + k) * H_;
    const float* wn = Whh + (size_t)(2 * H_ + k) * H_;
    const float b_r = bhhp[k], b_z = bhhp[H_ + k], b_n = bhhp[2 * H_ + k];
    unsigned* gbar = bars + (dir * 2 + bh) * 64;
    unsigned stamp = 0;

    for (int t = 0; t < S_; ++t) {
        const float* hin = encrot + (size_t)t * (2 * B_ * H_) + (size_t)dir * (B_ * H_);
        float* hout = encrot + (size_t)(t + 1) * (2 * B_ * H_) + (size_t)dir * (B_ * H_);
        const float* hsrc = hin + (size_t)bh * 16 * H_;
        for (int i = tid * 4; i < 16 * H_; i += 1024) {
            int r = i >> 9, cix = i & 511;
            *(float4*)&hL[r * 516 + cix] = *(const float4*)(hsrc + i);
        }
        __syncthreads();
        float ar = 0.f, az = 0.f, an = 0.f;
        const float* hv = &hL[bl * 516];
#pragma unroll 4
        for (int j = 0; j < H_; j += 4) {
            float4 h4 = *(const float4*)(hv + j);
            float4 r4 = *(const float4*)(wr + j);
            float4 z4 = *(const float4*)(wz + j);
            float4 n4 = *(const float4*)(wn + j);
            ar += h4.x * r4.x + h4.y * r4.y + h4.z * r4.z + h4.w * r4.w;
            az += h4.x * z4.x + h4.y * z4.y + h4.z * z4.z + h4.w * z4.w;
            an += h4.x * n4.x + h4.y * n4.y + h4.z * n4.z + h4.w * n4.w;
        }
        const float* gxr = gx + ((size_t)t * B_ + b) * G3_;
        float xr = gxr[k], xz = gxr[H_ + k], xn = gxr[2 * H_ + k];
        float rg = 1.f / (1.f + expf(-(xr + ar + b_r)));
        float zg = 1.f / (1.f + expf(-(xz + az + b_z)));
        float ng = tanhf(xn + rg * (an + b_n));
        float hp = hL[bl * 516 + k];
        float h2 = (1.f - zg) * ng + zg * hp;
        ato_stf(hout + (size_t)b * H_ + k, h2);
        int s_out = dir ? (S_ - 1 - t) : t;
        enc_bt[((size_t)b * S_ + s_out) * (2 * H_) + dir * H_ + k] = h2;
        ++stamp;
        flag_bar(gbar, kc, 32, stamp);
    }
    fast_barN(bars + 1024, bid, 8);    // both dirs done

    {
        const int b2 = bid & 31, ih = bid >> 5;
        float* hc = hL;
        const float* hfin = encrot + (size_t)S_ * (2 * B_ * H_);
        const float* hf  = hfin + (size_t)b2 * H_;
        const float* hbk = hfin + (size_t)B_ * H_ + (size_t)b2 * H_;
        for (int i = tid; i < H_; i += 256) { hc[i] = hf[i]; hc[H_ + i] = hbk[i]; }
        __syncthreads();
        if (tid < 128) {
            int i = ih * 128 + tid;
            const float* w = fcW + (size_t)i * (2 * H_);
            float acc = 0.f;
            for (int j = 0; j < 2 * H_; j += 4) {
                float4 a4 = *(const float4*)&hc[j];
                float4 w4 = *(const float4*)(w + j);
                acc += a4.x * w4.x + a4.y * w4.y + a4.z * w4.z + a4.w * w4.w;
            }
            ato_stf(hT0 + (size_t)b2 * H_ + i, tanhf(acc + fcb[i]));
        }
    }
}

// ---------------------------------------------------------------------------
// PERSISTENT attention decoder v15: 256 blocks = (b 32) x (sq 8), TWO phases.
// P_ihw[grow][b*S+s] (precomputed, L2-resident per XCD) replaces in-loop
// Wih·w. Scores are k-separable: each block computes partial scores over its
// own 64 k (hwh LDS-local), P1 sums 8 partials -> EXACT softmax -> xw from
// P_ihw -> gates. w deferred: a[t] stored, cat w-cols rebuilt by wcat.
// Comm/step: h (2KB) + pscore (4KB). 2 flag barriers/step.
// ---------------------------------------------------------------------------
__global__ __launch_bounds__(256)
void dec_coop_kernel(const float* __restrict__ attn_W, const float* __restrict__ attn_v,
                     const float* __restrict__ enc_projB, const int* __restrict__ src,
                     const float* __restrict__ dWhh, const float* __restrict__ dbhh,
                     const float* __restrict__ P_ihw, const float* __restrict__ gx_emb,
                     float* __restrict__ cat, float* __restrict__ hT,
                     float* __restrict__ pscoreT, float* __restrict__ aLrot,
                     unsigned* __restrict__ bars)
{
    const int bid = blockIdx.x, tid = threadIdx.x;
    const int b = bid >> 3, sq = bid & 7;
    const int k0 = sq * 64;
    __shared__ float hA[512];
    __shared__ float hwhL[64], vLo[64];
    __shared__ float ghhL[192], xwL[192];
    __shared__ float psL[1024];          // [q8][128]
    __shared__ float scL[128], aL[128], maskL[128];
    __shared__ float red[2];
    unsigned* gbar = bars + 2048 + b * 64;
    unsigned stamp = 0;

    const int ps_s = tid >> 1, ps_h = tid & 1;
    // constant register slice: proj[ps_s][k0 + ps_h*32 + i]
    float projreg[32];
    {
        const float* pr = enc_projB + ((size_t)b * S_ + ps_s) * H_ + k0 + ps_h * 32;
#pragma unroll
        for (int i = 0; i < 32; i += 4) {
            float4 v = *(const float4*)(pr + i);
            projreg[i] = v.x; projreg[i + 1] = v.y; projreg[i + 2] = v.z; projreg[i + 3] = v.w;
        }
    }
    if (tid < 64) vLo[tid] = attn_v[k0 + tid];
    if (tid < 128) maskL[tid] = (src[b * S_ + tid] != 0) ? 1.f : 0.f;

    // P0 row task (constant): tid<64 -> W_h row; else Whh row
    const float* w0row;
    float bias0 = 0.f;
    if (tid < 64) w0row = attn_W + (size_t)(k0 + tid) * G3_;
    else {
        int rr = tid - 64;
        int grow = (rr >> 6) * H_ + k0 + (rr & 63);
        w0row = dWhh + (size_t)grow * H_;
        bias0 = dbhh[grow];
    }
    // P_ihw row pointer for xw (threads 0..191)
    const float* prow = P_ihw;
    if (tid < 192) {
        int grow = (tid >> 6) * H_ + k0 + (tid & 63);
        prow = P_ihw + (size_t)grow * MBS_ + (size_t)b * S_;
    }

    for (int t = 0; t < TD_; ++t) {
        const int pp = t & 1;
        const float* hin = hT + (size_t)pp * (B_ * H_);
        float* hout = hT + (size_t)(1 - pp) * (B_ * H_);
        float* cat_t = cat + (size_t)t * B_ * CATK_;

        // ---- P0: h -> hwh(LDS, own 64 k) + ghh(LDS, 192) -> partial scores ----
        for (int j = tid; j < H_; j += 256) hA[j] = ato_ldf(hin + (size_t)b * H_ + j);
        __syncthreads();
        {
            float a0 = 0.f, a1 = 0.f;
            for (int j = 0; j < H_; j += 8) {
                float4 w0 = *(const float4*)(w0row + j);
                float4 w1 = *(const float4*)(w0row + j + 4);
                float4 h0 = *(const float4*)&hA[j];
                float4 h1 = *(const float4*)&hA[j + 4];
                a0 += w0.x * h0.x + w0.y * h0.y + w0.z * h0.z + w0.w * h0.w;
                a1 += w1.x * h1.x + w1.y * h1.y + w1.z * h1.z + w1.w * h1.w;
            }
            float acc = a0 + a1;
            if (tid < 64) hwhL[tid] = acc;
            else ghhL[tid - 64] = acc + bias0;
        }
        __syncthreads();
        {
            const float* hw = hwhL + ps_h * 32;
            const float* vv = vLo + ps_h * 32;
            float acc = 0.f;
#pragma unroll
            for (int i = 0; i < 32; i++) {
                float x = hw[i] + projreg[i];
                float e2 = __expf(2.f * x);
                acc += vv[i] * (1.f - 2.f / (e2 + 1.f));
            }
            acc += __shfl_xor(acc, 1);
            if (ps_h == 0) ato_stf(pscoreT + (size_t)b * 1024 + sq * 128 + ps_s, acc);
        }
        ++stamp;
        flag_bar(gbar, sq, 8, stamp);

        // ---- P1: sum partials -> exact softmax -> xw (P_ihw) -> gates ----
        for (int i = tid; i < 1024; i += 256)
            psL[i] = ato_ldf(pscoreT + (size_t)b * 1024 + i);
        __syncthreads();
        if (tid < 128) {
            float s = 0.f;
#pragma unroll
            for (int q = 0; q < 8; q++) s += psL[q * 128 + tid];
            scL[tid] = (maskL[tid] != 0.f) ? s : -1e10f;
        }
        __syncthreads();
        if (tid < 64) {
            float m = fmaxf(scL[tid], scL[tid + 64]);
#pragma unroll
            for (int off = 1; off < 64; off <<= 1) m = fmaxf(m, __shfl_xor(m, off));
            if (tid == 0) red[0] = m;
        }
        __syncthreads();
        if (tid < 128) aL[tid] = expf(scL[tid] - red[0]);
        __syncthreads();
        if (tid < 64) {
            float sv = aL[tid] + aL[tid + 64];
#pragma unroll
            for (int off = 1; off < 64; off <<= 1) sv += __shfl_xor(sv, off);
            if (tid == 0) red[1] = sv;
        }
        __syncthreads();
        if (tid < 128) {
            float a = aL[tid] / red[1];
            aL[tid] = a;
            if (sq == 0) aLrot[((size_t)t * B_ + b) * S_ + tid] = a;
        }
        __syncthreads();
        if (tid < 192) {
            float a0 = 0.f, a1 = 0.f;
            for (int s = 0; s < S_; s += 8) {
                float4 p0 = *(const float4*)(prow + s);
                float4 p1 = *(const float4*)(prow + s + 4);
                a0 += aL[s + 0] * p0.x + aL[s + 1] * p0.y + aL[s + 2] * p0.z + aL[s + 3] * p0.w;
                a1 += aL[s + 4] * p1.x + aL[s + 5] * p1.y + aL[s + 6] * p1.z + aL[s + 7] * p1.w;
            }
            xwL[tid] = a0 + a1;
        }
        __syncthreads();
        if (tid < 64) {
            int k = k0 + tid;
            float hr = ghhL[tid], hz = ghhL[64 + tid], hn = ghhL[128 + tid];
            float xr = xwL[tid], xz = xwL[64 + tid], xn = xwL[128 + tid];
            const float* gxe = gx_emb + ((size_t)t * B_ + b) * G3_;
            float rg = 1.f / (1.f + expf(-(gxe[k] + xr + hr)));
            float zg = 1.f / (1.f + expf(-(gxe[H_ + k] + xz + hz)));
            float ng = tanhf(gxe[2 * H_ + k] + xn + rg * hn);
            float hp = hA[k];
            float h2 = (1.f - zg) * ng + zg * hp;
            ato_stf(hout + (size_t)b * H_ + k, h2);
            cat_t[(size_t)b * CATK_ + k] = h2;
        }
        ++stamp;
        flag_bar(gbar, sq, 8, stamp);
    }
}

// ---------------------------------------------------------------------------
// reconstruct weighted vectors into cat[:, 768:1792] from stored aL (r8-proven)
// grid = 512: (b 32, dc 16 chunks of 64 dims)
// ---------------------------------------------------------------------------
__global__ __launch_bounds__(256)
void wcat_kernel(const float* __restrict__ aLrot, const float* __restrict__ enc_bt,
                 float* __restrict__ cat)
{
    const int b = blockIdx.x & 31, dc = blockIdx.x >> 5;
    const int d0 = dc * 64;
    const int tid = threadIdx.x;
    __shared__ float ebt[128 * 64];
    __shared__ float aLs[128];
    __shared__ float partw[256];
    for (int i = tid; i < 128 * 16; i += 256) {
        int s = i >> 4, dq = (i & 15) * 4;
        float4 v = *(const float4*)(enc_bt + ((size_t)b * S_ + s) * (2 * H_) + d0 + dq);
        *(float4*)&ebt[s * 64 + dq] = v;
    }
    __syncthreads();
    for (int t = 0; t < TD_; t++) {
        if (tid < 128) aLs[tid] = aLrot[((size_t)t * B_ + b) * S_ + tid];
        __syncthreads();
        int d = tid & 63, sg = tid >> 6;
        float acc = 0.f;
        for (int s = sg * 32; s < sg * 32 + 32; s++) acc += aLs[s] * ebt[s * 64 + d];
        partw[tid] = acc;
        __syncthreads();
        if (tid < 64) {
            float w = partw[tid] + partw[tid + 64] + partw[tid + 128] + partw[tid + 192];
            cat[((size_t)t * B_ + b) * CATK_ + H_ + E_ + d0 + tid] = w;
        }
        __syncthreads();
    }
}

// ---------------------------------------------------------------------------
// split fp32 -> bf16 hi/lo (zero-pad beyond `valid`)
// ---------------------------------------------------------------------------
__global__ __launch_bounds__(256)
void split_kernel(const float* __restrict__ src, unsigned short* __restrict__ hi,
                  unsigned short* __restrict__ lo, long total, long valid)
{
    long i4 = ((long)blockIdx.x * 256 + threadIdx.x) * 4;
    if (i4 >= total) return;
    float4 v;
    if (i4 < valid) v = *(const float4*)(src + i4);
    else { v.x = v.y = v.z = v.w = 0.f; }
    float f[4] = {v.x, v.y, v.z, v.w};
    unsigned short h[4], l[4];
#pragma unroll
    for (int j = 0; j < 4; j++) {
        h[j] = bf16_rne(f[j]);
        float hf = __uint_as_float((unsigned)h[j] << 16);
        l[j] = bf16_rne(f[j] - hf);
    }
    *(ushort4*)(hi + i4) = make_ushort4(h[0], h[1], h[2], h[3]);
    *(ushort4*)(lo + i4) = make_ushort4(l[0], l[1], l[2], l[3]);
}

// ---------------------------------------------------------------------------
// split-bf16 MFMA GEMM (hh+hl+lh = fp32-accurate).
// TRANS=0: fc1 path (bias, t/b-mapped rows, M-guard).  TRANS=1: C[col][m].
// ---------------------------------------------------------------------------
template<int KLEN, int TRANS>
__global__ __launch_bounds__(256)
void mfma_gemm_kernel(const unsigned short* __restrict__ Ahi,
                      const unsigned short* __restrict__ Alo,
                      const float* __restrict__ W, int ldw,
                      const float* __restrict__ bias,
                      float* __restrict__ C, int ldc, int Mvalid)
{
    __shared__ unsigned short lA[2][128][40];
    __shared__ unsigned short lW[2][128][40];
    const int tid = threadIdx.x;
    const int m0 = blockIdx.x * 128, n0 = blockIdx.y * 128;
    const int w = tid >> 6, lane = tid & 63;
    const int wm = w >> 1, wn = w & 1;
    const int frow = lane & 15, fk = (lane >> 4) * 8;

    f32x4 acc[4][4];
#pragma unroll
    for (int mi = 0; mi < 4; mi++)
#pragma unroll
        for (int ni = 0; ni < 4; ni++) acc[mi][ni] = (f32x4){0.f, 0.f, 0.f, 0.f};

    const int srow = tid >> 1;
    const int skq = (tid & 1) * 16;

    const unsigned short* gAhi = Ahi + (size_t)(m0 + srow) * KLEN + skq;
    const unsigned short* gAlo = Alo + (size_t)(m0 + srow) * KLEN + skq;
    const float*          gW   = W   + (size_t)(n0 + srow) * ldw + skq;

    int4 rAh0, rAh1, rAl0, rAl1;
    float4 rW0, rW1, rW2, rW3;

#define MG_LOAD(kb)                                         \
    do {                                                    \
        rAh0 = *(const int4*)(gAhi + (kb));                 \
        rAh1 = *(const int4*)(gAhi + (kb) + 8);             \
        rAl0 = *(const int4*)(gAlo + (kb));                 \
        rAl1 = *(const int4*)(gAlo + (kb) + 8);             \
        rW0  = *(const float4*)(gW + (kb));                 \
        rW1  = *(const float4*)(gW + (kb) + 4);             \
        rW2  = *(const float4*)(gW + (kb) + 8);             \
        rW3  = *(const float4*)(gW + (kb) + 12);            \
    } while (0)

    MG_LOAD(0);

    for (int kb = 0; kb < KLEN; kb += 32) {
        __syncthreads();
        *(int4*)&lA[0][srow][skq]     = rAh0;
        *(int4*)&lA[0][srow][skq + 8] = rAh1;
        *(int4*)&lA[1][srow][skq]     = rAl0;
        *(int4*)&lA[1][srow][skq + 8] = rAl1;
        {
            float f[16] = {rW0.x, rW0.y, rW0.z, rW0.w, rW1.x, rW1.y, rW1.z, rW1.w,
                           rW2.x, rW2.y, rW2.z, rW2.w, rW3.x, rW3.y, rW3.z, rW3.w};
            unsigned hp[8], lp[8];
#pragma unroll
            for (int j = 0; j < 8; j++) {
                float x0 = f[2 * j], x1 = f[2 * j + 1];
                unsigned short h0 = bf16_rne(x0), h1 = bf16_rne(x1);
                float r0 = x0 - __uint_as_float((unsigned)h0 << 16);
                float r1 = x1 - __uint_as_float((unsigned)h1 << 16);
                hp[j] = (unsigned)h0 | ((unsigned)h1 << 16);
                lp[j] = (unsigned)bf16_rne(r0) | ((unsigned)bf16_rne(r1) << 16);
            }
            *(int4*)&lW[0][srow][skq]     = make_int4(hp[0], hp[1], hp[2], hp[3]);
            *(int4*)&lW[0][srow][skq + 8] = make_int4(hp[4], hp[5], hp[6], hp[7]);
            *(int4*)&lW[1][srow][skq]     = make_int4(lp[0], lp[1], lp[2], lp[3]);
            *(int4*)&lW[1][srow][skq + 8] = make_int4(lp[4], lp[5], lp[6], lp[7]);
        }
        __syncthreads();
        if (kb + 32 < KLEN) MG_LOAD(kb + 32);

        bf16x8 a[2][4];
#pragma unroll
        for (int mi = 0; mi < 4; mi++) {
            int r = wm * 64 + mi * 16 + frow;
            a[0][mi] = *(const bf16x8*)&lA[0][r][fk];
            a[1][mi] = *(const bf16x8*)&lA[1][r][fk];
        }
#pragma unroll
        for (int ni = 0; ni < 4; ni++) {
            int r = wn * 64 + ni * 16 + frow;
            bf16x8 bh = *(const bf16x8*)&lW[0][r][fk];
            bf16x8 bl = *(const bf16x8*)&lW[1][r][fk];
#pragma unroll
            for (int mi = 0; mi < 4; mi++) {
                acc[mi][ni] = __builtin_amdgcn_mfma_f32_16x16x32_bf16(a[0][mi], bh, acc[mi][ni], 0, 0, 0);
                acc[mi][ni] = __builtin_amdgcn_mfma_f32_16x16x32_bf16(a[1][mi], bh, acc[mi][ni], 0, 0, 0);
                acc[mi][ni] = __builtin_amdgcn_mfma_f32_16x16x32_bf16(a[0][mi], bl, acc[mi][ni], 0, 0, 0);
            }
        }
    }
#undef MG_LOAD

#pragma unroll
    for (int ni = 0; ni < 4; ni++) {
        int col = n0 + wn * 64 + ni * 16 + frow;
        float bc = TRANS ? 0.f : bias[col];
#pragma unroll
        for (int mi = 0; mi < 4; mi++) {
            int mbase = m0 + wm * 64 + mi * 16 + (lane >> 4) * 4;
            f32x4 v = acc[mi][ni];
            if (TRANS) {
                float4 o; o.x = v[0]; o.y = v[1]; o.z = v[2]; o.w = v[3];
                *(float4*)(C + (size_t)col * ldc + mbase) = o;
            } else {
#pragma unroll
                for (int r = 0; r < 4; r++) {
                    int m = mbase + r;
                    if (m < Mvalid) {
                        int tt = m >> 5, bb2 = m & 31;
                        C[((size_t)bb2 * T_ + tt) * ldc + col] = v[r] + bc;
                    }
                }
            }
        }
    }
}

// ---------------------------------------------------------------------------
__global__ __launch_bounds__(256)
void argmax_kernel(const float* __restrict__ outp, float* __restrict__ preds)
{
    int row = blockIdx.x;
    int t = row >> 5, b = row & 31;
    const float* p = outp + ((size_t)b * T_ + t) * V_;
    int tid = threadIdx.x;
    float best = -3.4e38f; int bi = V_;
    for (int i = tid; i < V_; i += 256) {
        float v = p[i];
        if (v > best) { best = v; bi = i; }
    }
    __shared__ float bv[256];
    __shared__ int bidx[256];
    bv[tid] = best; bidx[tid] = bi;
    __syncthreads();
    for (int off = 128; off > 0; off >>= 1) {
        if (tid < off) {
            float v2 = bv[tid + off]; int i2 = bidx[tid + off];
            if (v2 > bv[tid] || (v2 == bv[tid] && i2 < bidx[tid])) { bv[tid] = v2; bidx[tid] = i2; }
        }
        __syncthreads();
    }
    if (tid == 0) preds[(size_t)b * T_ + t] = (float)bidx[0];
}

// ---------------------------------------------------------------------------
__global__ __launch_bounds__(256)
void zero_tail_kernel(float* __restrict__ outp, float* __restrict__ preds)
{
    int tid = blockIdx.x * 256 + threadIdx.x;
    if (tid < B_ * V_) {
        int b = tid / V_;
        int c = tid % V_;
        outp[((size_t)b * T_ + (T_ - 1)) * V_ + c] = 0.f;
    }
    if (tid < B_) preds[(size_t)tid * T_ + (T_ - 1)] = 0.f;
}

// ---------------------------------------------------------------------------
extern "C" void kernel_launch(void* const* d_in, const int* in_sizes, int n_in,
                              void* d_out, int out_size, void* d_ws, size_t ws_size,
                              hipStream_t stream)
{
    (void)in_sizes; (void)n_in; (void)out_size;
    const int*   src     = (const int*)d_in[0];
    const int*   tgt     = (const int*)d_in[1];
    const float* enc_emb = (const float*)d_in[2];
    const float* Wih_f   = (const float*)d_in[3];
    const float* Whh_f   = (const float*)d_in[4];
    const float* bih_f   = (const float*)d_in[5];
    const float* bhh_f   = (const float*)d_in[6];
    const float* Wih_b   = (const float*)d_in[7];
    const float* Whh_b   = (const float*)d_in[8];
    const float* bih_b   = (const float*)d_in[9];
    const float* bhh_b   = (const float*)d_in[10];
    const float* fcW     = (const float*)d_in[11];
    const float* fcb     = (const float*)d_in[12];
    const float* dec_emb = (const float*)d_in[13];
    const float* attn_W  = (const float*)d_in[14];
    const float* attn_b  = (const float*)d_in[15];
    const float* attn_v  = (const float*)d_in[16];
    const float* dWih    = (const float*)d_in[17];
    const float* dWhh    = (const float*)d_in[18];
    const float* dbih    = (const float*)d_in[19];
    const float* dbhh    = (const float*)d_in[20];
    const float* fc1W    = (const float*)d_in[21];
    const float* fc1b    = (const float*)d_in[22];
    (void)dbih;

    // ws layout
    float* ws     = (float*)d_ws;
    float* cat    = ws;                                  // 3,612,672 f
    float* gx_emb = cat + (size_t)TD_ * B_ * CATK_;      // 3,096,576 f
    int*   tokf   = (int*)(gx_emb + (size_t)TD_ * B_ * G3_);
    int*   tokb   = tokf + 4096;
    int*   tokd   = tokb + 4096;
    unsigned* bars = (unsigned*)(tokd + 4096);           // 4096 u: enc flags 0..255,
                                                         // enc full @1024, dec flags @2048
    unsigned short* Ahi = (unsigned short*)(bars + 4096);
    unsigned short* Alo = Ahi + (size_t)MPAD_ * CATK_;
    size_t ws_req = (size_t)((char*)(Alo + (size_t)MPAD_ * CATK_) - (char*)d_ws);
    const bool use_mfma = (ws_size >= ws_req);

    // d_out scratch (fully overwritten by fc1 + zero_tail afterwards)
    float* dout      = (float*)d_out;
    float* gxf       = dout;                                        // 6,291,456
    float* gxb       = gxf + (size_t)S_ * B_ * G3_;                 // 6,291,456
    float* enc_bt    = gxb + (size_t)S_ * B_ * G3_;                 // 4,194,304
    float* enc_projB = enc_bt + (size_t)B_ * S_ * 2 * H_;           // 2,097,152
    float* encrot    = enc_projB + (size_t)B_ * S_ * H_;            // 129 x 32,768
    float* hT        = encrot + (size_t)(S_ + 1) * 2 * B_ * H_;     // 2 x 16,384 ([pp][b][k])
    float* pscoreT   = hT + 2 * B_ * H_;                            // 32,768 ([b][q8][128])
    float* aLrot     = pscoreT + B_ * 8 * 128;                      // 258,048 ([t][b][s])
    float* P_ihw     = aLrot + (size_t)TD_ * B_ * S_;               // 6,291,456 ([G3_][MBS_])
    unsigned short* Bhi = (unsigned short*)(P_ihw + (size_t)G3_ * MBS_);  // 4,194,304 us
    unsigned short* Blo = Bhi + (size_t)MBS_ * 1024;                      // 4,194,304 us
    float* preds     = dout + (size_t)B_ * T_ * V_;

    dim3 thr(256);

    hipLaunchKernelGGL(prep_kernel, dim3(256), thr, 0, stream,
                       src, tgt, tokf, tokb, tokd, encrot, bars);
    hipLaunchKernelGGL(emb_cat_kernel, dim3(TD_ * B_), thr, 0, stream, tokd, dec_emb, cat);

    hipLaunchKernelGGL((gemm128_kernel<1, 0>), dim3(G3_ / 128, (S_ * B_) / 128), thr, 0, stream,
                       (const float*)nullptr, 0, tokf, enc_emb, Wih_f, E_, bih_f,
                       gxf, G3_, S_ * B_, G3_, E_);
    hipLaunchKernelGGL((gemm128_kernel<1, 0>), dim3(G3_ / 128, (S_ * B_) / 128), thr, 0, stream,
                       (const float*)nullptr, 0, tokb, enc_emb, Wih_b, E_, bih_b,
                       gxb, G3_, S_ * B_, G3_, E_);

    // encoder recurrence + enc_fc in ONE launch (128 blocks, flag barriers)
    hipLaunchKernelGGL(enc_coop_kernel, dim3(128), thr, 0, stream,
                       gxf, gxb, Whh_f, bhh_f, Whh_b, bhh_b, encrot, enc_bt,
                       fcW, fcb, hT /* slot 0, [b][k] */, bars);

    hipLaunchKernelGGL((gemm128_kernel<0, 0>), dim3(H_ / 128, (B_ * S_) / 128), thr, 0, stream,
                       enc_bt, 2 * H_, (const int*)nullptr, (const float*)nullptr,
                       attn_W + H_, G3_, attn_b, enc_projB, H_, B_ * S_, H_, 2 * H_);

    hipLaunchKernelGGL((gemm128_kernel<1, 0>), dim3(G3_ / 128, (TD_ * B_ + 127) / 128), thr, 0, stream,
                       (const float*)nullptr, 0, tokd, dec_emb, dWih, DIN_, dbih,
                       gx_emb, G3_, TD_ * B_, G3_, E_);

    // P_ihw = (dWih w-cols) x enc_bt^T via split-bf16 MFMA -> [G3_][MBS_]
    hipLaunchKernelGGL(split_kernel, dim3((MBS_ * 1024 / 4 + 255) / 256), thr, 0, stream,
                       enc_bt, Bhi, Blo, (long)MBS_ * 1024, (long)MBS_ * 1024);
    hipLaunchKernelGGL((mfma_gemm_kernel<1024, 1>), dim3(MBS_ / 128, G3_ / 128), thr, 0, stream,
                       Bhi, Blo, dWih + E_, DIN_, (const float*)nullptr,
                       P_ihw, MBS_, MBS_);

    // decoder recurrence in ONE launch (256 blocks, 2 phases/step)
    hipLaunchKernelGGL(dec_coop_kernel, dim3(256), thr, 0, stream,
                       attn_W, attn_v, enc_projB, src,
                       dWhh, dbhh, P_ihw, gx_emb, cat, hT, pscoreT, aLrot,
                       bars);

    // rebuild cat w-cols from stored attention weights
    hipLaunchKernelGGL(wcat_kernel, dim3(512), thr, 0, stream, aLrot, enc_bt, cat);

    if (use_mfma) {
        hipLaunchKernelGGL(split_kernel, dim3((MPAD_ * CATK_ / 4 + 255) / 256), thr, 0, stream,
                           cat, Ahi, Alo, (long)MPAD_ * CATK_, (long)TD_ * B_ * CATK_);
        hipLaunchKernelGGL((mfma_gemm_kernel<CATK_, 0>), dim3(MPAD_ / 128, V_ / 128), thr, 0, stream,
                           Ahi, Alo, fc1W, CATK_, fc1b, dout, V_, TD_ * B_);
    } else {
        hipLaunchKernelGGL((gemm128_kernel<0, 1>), dim3(V_ / 128, (TD_ * B_ + 127) / 128), thr, 0, stream,
                           cat, CATK_, (const int*)nullptr, (const float*)nullptr,
                           fc1W, CATK_, fc1b, dout, V_, TD_ * B_, V_, CATK_);
    }

    hipLaunchKernelGGL(argmax_kernel, dim3(TD_ * B_), thr, 0, stream, dout, preds);
    hipLaunchKernelGGL(zero_tail_kernel, dim3((B_ * V_ + 255) / 256), thr, 0, stream, dout, preds);
}